// Round 16
// baseline (339.383 us; speedup 1.0000x reference)
//
#include <hip/hip_runtime.h>
#include <hip/hip_bf16.h>
#include <stdint.h>

using bf16 = __hip_bfloat16;
typedef __attribute__((ext_vector_type(8))) short short8;
typedef __attribute__((ext_vector_type(4))) float f32x4;
typedef __attribute__((ext_vector_type(16))) float f32x16;

#define MFMA16(a,b,c) __builtin_amdgcn_mfma_f32_16x16x32_bf16(a,b,c,0,0,0)
#define MFMA32(a,b,c) __builtin_amdgcn_mfma_f32_32x32x16_bf16(a,b,c,0,0,0)

__device__ __forceinline__ void gload_lds16(const void* g, void* l) {
  __builtin_amdgcn_global_load_lds((const __attribute__((address_space(1))) void*)g,
                                   (__attribute__((address_space(3))) void*)l, 16, 0, 0);
}

__device__ __forceinline__ short bf_bits(float f) {
  bf16 h = __float2bfloat16(f);
  return *reinterpret_cast<short*>(&h);
}
// hardware packed f32->bf16 (RNE), low = a, high = b  [T12]
__device__ __forceinline__ unsigned int pk2(float a, float b) {
  unsigned int r;
  asm("v_cvt_pk_bf16_f32 %0, %1, %2" : "=v"(r) : "v"(a), "v"(b));
  return r;
}
__device__ __forceinline__ float bf2f(short s) {
  return __uint_as_float((unsigned int)(unsigned short)s << 16);
}
__device__ __forceinline__ float exp2g(float x) { return __builtin_amdgcn_exp2f(x); }

// ---------------- fused prep: x f32->bf16 (blocks 0..8191) + 4 weight transposes ----------------
__global__ __launch_bounds__(256) void prep_k(const float* __restrict__ x, bf16* __restrict__ xb,
                                              const float* __restrict__ wq, const float* __restrict__ wk,
                                              const float* __restrict__ wv, const float* __restrict__ wp,
                                              bf16* __restrict__ wqkvT, bf16* __restrict__ wpT) {
  __shared__ float tile[32][33];
  int bid = blockIdx.x;
  if (bid < 8192) {  // x conversion, 8 elems/thread
    size_t i = ((size_t)bid * 256 + threadIdx.x) * 8;
    float4 a = *(const float4*)(x + i);
    float4 b = *(const float4*)(x + i + 4);
    short8 pk;
    pk[0] = bf_bits(a.x); pk[1] = bf_bits(a.y); pk[2] = bf_bits(a.z); pk[3] = bf_bits(a.w);
    pk[4] = bf_bits(b.x); pk[5] = bf_bits(b.y); pk[6] = bf_bits(b.z); pk[7] = bf_bits(b.w);
    *(short8*)(xb + i) = pk;
    return;
  }
  bid -= 8192;
  const float* in; bf16* out; int N, loc;
  constexpr int K = 2048;
  if (bid < 4096)      { in = wq; out = wqkvT;                        N = 2048; loc = bid; }
  else if (bid < 5120) { in = wk; out = wqkvT + (size_t)2048 * K;     N = 512;  loc = bid - 4096; }
  else if (bid < 6144) { in = wv; out = wqkvT + (size_t)2560 * K;     N = 512;  loc = bid - 5120; }
  else                 { in = wp; out = wpT;                          N = 2048; loc = bid - 6144; }
  int nb = N >> 5;
  int n0 = (loc % nb) * 32, k0 = (loc / nb) * 32;
  int tx = threadIdx.x & 31, ty = threadIdx.x >> 5;  // 32 x 8
#pragma unroll
  for (int j = 0; j < 4; ++j) {
    int kk = ty + j * 8;
    tile[kk][tx] = in[(size_t)(k0 + kk) * N + n0 + tx];
  }
  __syncthreads();
#pragma unroll
  for (int j = 0; j < 4; ++j) {
    int nn = ty + j * 8;
    out[(size_t)(n0 + nn) * K + k0 + tx] = __float2bfloat16(tile[tx][nn]);
  }
}

// ---------------- 256x256 8-phase bf16 GEMM: C[.][ldC] = A[M][K] * Bt[N][K]^T ----------------
#define PHASE(buf, i0, ...)                                                       \
  {                                                                               \
    short8 a00 = ldA(buf, i0, 0), a01 = ldA(buf, i0, 1);                          \
    short8 a10 = ldA(buf, (i0) + 1, 0), a11 = ldA(buf, (i0) + 1, 1);              \
    __VA_ARGS__;                                                                  \
    __builtin_amdgcn_s_barrier();                                                 \
    asm volatile("s_waitcnt lgkmcnt(0)" ::: "memory");                            \
    __builtin_amdgcn_s_setprio(1);                                                \
    _Pragma("unroll") for (int j = 0; j < 4; ++j) {                               \
      acc[i0][j] = MFMA16(a00, bf_[2 * j], acc[i0][j]);                           \
      acc[i0][j] = MFMA16(a01, bf_[2 * j + 1], acc[i0][j]);                       \
      acc[(i0) + 1][j] = MFMA16(a10, bf_[2 * j], acc[(i0) + 1][j]);               \
      acc[(i0) + 1][j] = MFMA16(a11, bf_[2 * j + 1], acc[(i0) + 1][j]);           \
    }                                                                             \
    __builtin_amdgcn_s_setprio(0);                                                \
  }
#define LOADB(buf)                                                                \
  _Pragma("unroll") for (int j = 0; j < 4; ++j) {                                 \
    bf_[2 * j] = ldB(buf, j, 0);                                                  \
    bf_[2 * j + 1] = ldB(buf, j, 1);                                              \
  }
#define BAR __builtin_amdgcn_s_barrier()

template <typename OutT>
__global__ __launch_bounds__(512, 2) void gemm256(const bf16* __restrict__ A,
                                                  const bf16* __restrict__ Bt,
                                                  OutT* __restrict__ C, int K,
                                                  int NT, int ldC) {
  __shared__ char lds[131072];
  const int tid = threadIdx.x, lane = tid & 63, w = tid >> 6;
  const int wm = w >> 2, wn = w & 3;
  const int bx = blockIdx.x;
  const int chunk = gridDim.x >> 3;
  const int wgid = (bx & 7) * chunk + (bx >> 3);   // XCD-bijective (grid % 8 == 0)
  const int m0 = (wgid / NT) * 256, n0 = (wgid % NT) * 256;
  const int lm = lane & 15;
  const int sw = (lane & 7) << 4;
  const int g16 = (lane >> 4) << 4;
  const size_t strideAB = (size_t)K * 2;  // bytes per row

  auto stageA = [&](int buf, int h, int t) {
#pragma unroll
    for (int p2 = 0; p2 < 2; ++p2) {
      int off = tid * 16 + p2 * 8192;
      int row = off >> 7, cb = off & 127;
      int scb = cb ^ ((row & 7) << 4);
      gload_lds16((const char*)A + (size_t)(m0 + h * 128 + row) * strideAB + t * 128 + scb,
                  lds + buf * 65536 + h * 16384 + off);
    }
  };
  auto stageB = [&](int buf, int h, int t) {
#pragma unroll
    for (int p2 = 0; p2 < 2; ++p2) {
      int off = tid * 16 + p2 * 8192;
      int row = off >> 7, cb = off & 127;
      int scb = cb ^ ((row & 7) << 4);
      gload_lds16((const char*)Bt + (size_t)(n0 + h * 128 + row) * strideAB + t * 128 + scb,
                  lds + buf * 65536 + 32768 + h * 16384 + off);
    }
  };
  auto ldA = [&](int buf, int i, int ks) {
    int row = wm * 128 + i * 16 + lm;
    return *(const short8*)(lds + buf * 65536 + row * 128 + ((ks * 64 + g16) ^ sw));
  };
  auto ldB = [&](int buf, int j, int ks) {
    int row = wn * 64 + j * 16 + lm;
    return *(const short8*)(lds + buf * 65536 + 32768 + row * 128 + ((ks * 64 + g16) ^ sw));
  };

  f32x4 acc[8][4] = {};
  short8 bf_[8];
  const int niter = K / 128;

  stageA(0, 0, 0); stageA(0, 1, 0); stageB(0, 0, 0); stageB(0, 1, 0);
  stageB(1, 0, 1); stageB(1, 1, 1);
  asm volatile("s_waitcnt vmcnt(4)" ::: "memory");
  BAR;

  for (int i = 0; i < niter; ++i) {
    const int t0 = 2 * i, t1 = 2 * i + 1;
    const bool nl = (i + 1 < niter);
    LOADB(0);
    PHASE(0, 0, stageA(1, 0, t1)); BAR;
    PHASE(0, 2, stageA(1, 1, t1)); BAR;
    PHASE(0, 4, if (nl) stageB(0, 0, t0 + 2)); BAR;
    PHASE(0, 6, if (nl) stageB(0, 1, t0 + 2));
    if (nl) { asm volatile("s_waitcnt vmcnt(4)" ::: "memory"); }
    else    { asm volatile("s_waitcnt vmcnt(0)" ::: "memory"); }
    BAR;
    LOADB(1);
    PHASE(1, 0, if (nl) stageA(0, 0, t0 + 2)); BAR;
    PHASE(1, 2, if (nl) stageA(0, 1, t0 + 2)); BAR;
    PHASE(1, 4, if (nl) stageB(1, 0, t1 + 2)); BAR;
    PHASE(1, 6, if (nl) stageB(1, 1, t1 + 2));
    if (nl) { asm volatile("s_waitcnt vmcnt(4)" ::: "memory"); }
    BAR;
  }

  if constexpr (sizeof(OutT) == 2) {
    __syncthreads();
    bf16* sC = (bf16*)lds;
#pragma unroll
    for (int i = 0; i < 8; ++i) {
      int row = wm * 128 + i * 16 + (lane >> 4) * 4;
#pragma unroll
      for (int j = 0; j < 4; ++j) {
        int col = wn * 64 + j * 16 + lm;
#pragma unroll
        for (int r = 0; r < 4; ++r) sC[(row + r) * 256 + col] = __float2bfloat16(acc[i][j][r]);
      }
    }
    __syncthreads();
#pragma unroll
    for (int p = 0; p < 16; ++p) {
      int off = tid * 16 + p * 8192;
      int row = off >> 9, cb = off & 511;
      *(short8*)((char*)C + ((size_t)(m0 + row) * ldC + n0) * 2 + cb) =
          *(const short8*)(lds + off);
    }
  } else {
    // f32 epilogue: LDS-staged in two 128-row halves, coalesced 16B stores
    float* sCf = (float*)lds;
#pragma unroll
    for (int half = 0; half < 2; ++half) {
      __syncthreads();
      if (wm == half) {
#pragma unroll
        for (int i = 0; i < 8; ++i) {
          int row = i * 16 + (lane >> 4) * 4;   // local 0..127
#pragma unroll
          for (int j = 0; j < 4; ++j) {
            int col = wn * 64 + j * 16 + lm;
#pragma unroll
            for (int r = 0; r < 4; ++r) sCf[(row + r) * 256 + col] = acc[i][j][r];
          }
        }
      }
      __syncthreads();
#pragma unroll
      for (int p = 0; p < 16; ++p) {
        int off = tid * 16 + p * 8192;          // 0..131071 bytes
        int row = off >> 10, cb = off & 1023;   // 1024 B per 256-f32 row
        *(f32x4*)((char*)C + ((size_t)(m0 + half * 128 + row) * ldC + n0) * 4 + cb) =
            *(const f32x4*)(lds + off);
      }
    }
  }
}

// ---------------- KV projection GEMM (128x128, m97 structure) + fused epilogue ----------------
__global__ __launch_bounds__(256) void gemm_kv(const bf16* __restrict__ A,
                                               const bf16* __restrict__ Bt,
                                               bf16* __restrict__ qkv,
                                               bf16* __restrict__ vtb,
                                               const float* __restrict__ cosp,
                                               const float* __restrict__ sinp) {
  constexpr int BM = 128, BN = 128, BK = 64, K = 2048, QKVW = 3072, T = 2048, SCP = 132;
  __shared__ char smem[BM * SCP * 2];
  bf16* sA = (bf16*)smem;
  bf16* sB = (bf16*)(smem + 16384);
  int tid = threadIdx.x;
  int lane = tid & 63, w = tid >> 6;
  int flat = blockIdx.x;
  int wgid = (flat & 7) * (gridDim.x >> 3) + (flat >> 3);
  int m0 = (wgid >> 3) * BM, n0 = (wgid & 7) * BN;
  int wm = (w >> 1) * 64, wn = (w & 1) * 64;
  f32x4 acc[4][4] = {};
  for (int kt = 0; kt < K / BK; ++kt) {
    __syncthreads();
    int kb = kt * BK;
#pragma unroll
    for (int it = 0; it < 4; ++it) {
      int off = tid * 16 + it * 4096;
      int row = off >> 7, cb = off & 127;
      gload_lds16((const char*)A + (((size_t)(m0 + row)) * K + kb) * 2 + cb, (char*)sA + off);
    }
#pragma unroll
    for (int it = 0; it < 4; ++it) {
      int off = tid * 16 + it * 4096;
      int row = off >> 7, cb = off & 127;
      gload_lds16((const char*)Bt + (((size_t)(n0 + row)) * K + kb) * 2 + cb, (char*)sB + off);
    }
    asm volatile("s_waitcnt vmcnt(0)" ::: "memory");
    __syncthreads();
#pragma unroll
    for (int ks = 0; ks < 2; ++ks) {
      short8 af[4], bfr[4];
#pragma unroll
      for (int i = 0; i < 4; ++i) {
        af[i]  = *(const short8*)(sA + (wm + i * 16 + (lane & 15)) * BK + ks * 32 + (lane >> 4) * 8);
        bfr[i] = *(const short8*)(sB + (wn + i * 16 + (lane & 15)) * BK + ks * 32 + (lane >> 4) * 8);
      }
#pragma unroll
      for (int i = 0; i < 4; ++i)
#pragma unroll
        for (int j = 0; j < 4; ++j)
          acc[i][j] = MFMA16(af[i], bfr[j], acc[i][j]);
    }
  }

  const int kvh = (n0 >> 7) & 3;
  const int b = m0 >> 11, t0 = m0 & (T - 1);
  bf16* sC = (bf16*)smem;
  __syncthreads();
  if (n0 >= 512) {
    // V tile: transposed store sC_T[d][t_local], then coalesced to vt
#pragma unroll
    for (int i = 0; i < 4; ++i) {
      int row = wm + i * 16 + (lane >> 4) * 4;
#pragma unroll
      for (int j = 0; j < 4; ++j) {
        int col = wn + j * 16 + (lane & 15);
#pragma unroll
        for (int r = 0; r < 4; ++r) sC[col * SCP + row + r] = __float2bfloat16(acc[i][j][r]);
      }
    }
    __syncthreads();
#pragma unroll
    for (int p = 0; p < 8; ++p) {
      int g = p * 2048 + tid * 8;
      int d = g >> 7, tb = g & 127;
      *(short8*)(vtb + ((size_t)((b * 4 + kvh) * 128 + d)) * T + t0 + tb) =
          *(const short8*)(sC + d * SCP + tb);
    }
  } else {
    // K tile: rope+RMS in LDS, linear store
#pragma unroll
    for (int i = 0; i < 4; ++i) {
      int row = wm + i * 16 + (lane >> 4) * 4;
#pragma unroll
      for (int j = 0; j < 4; ++j) {
        int col = wn + j * 16 + (lane & 15);
#pragma unroll
        for (int r = 0; r < 4; ++r) sC[(row + r) * SCP + col] = __float2bfloat16(acc[i][j][r]);
      }
    }
    __syncthreads();
    for (int rr = 0; rr < 32; ++rr) {
      int row = w * 32 + rr;
      int t = t0 + row;
      float x1 = __bfloat162float(sC[row * SCP + lane]);
      float x2 = __bfloat162float(sC[row * SCP + lane + 64]);
      float c = cosp[t * 64 + lane], s = sinp[t * 64 + lane];
      float o1 = x1 * c - x2 * s;
      float o2 = x1 * s + x2 * c;
      float ss = o1 * o1 + o2 * o2;
#pragma unroll
      for (int m = 1; m < 64; m <<= 1) ss += __shfl_xor(ss, m, 64);
      float r = rsqrtf(ss * (1.f / 128.f) + 1e-5f);
      sC[row * SCP + lane] = __float2bfloat16(o1 * r);
      sC[row * SCP + lane + 64] = __float2bfloat16(o2 * r);
    }
    __syncthreads();
#pragma unroll
    for (int p = 0; p < 8; ++p) {
      int g = p * 2048 + tid * 8;
      int row = g >> 7, cb = g & 127;
      *(short8*)(qkv + (size_t)(m0 + row) * QKVW + 2048 + kvh * 128 + cb) =
          *(const short8*)(sC + row * SCP + cb);
    }
  }
}

// ---------------- flash attention: kv-split jobs for load balance ----------------
// 768 blocks = 12 jobs x 64 (b,h). Heavy q-tiles (qt 7..4) split into two kv-half jobs
// writing unnormalized partials (bf16 O + f32 m,l); qt 3..0 write y directly.
// Jobs ordered longest-first. combine_k merges partials.
__global__ __launch_bounds__(512, 2) void attn_k(const bf16* __restrict__ qkv,
                                                 const bf16* __restrict__ vt,
                                                 bf16* __restrict__ y,
                                                 bf16* __restrict__ pO,
                                                 float2* __restrict__ pML,
                                                 const float* __restrict__ cosp,
                                                 const float* __restrict__ sinp) {
  constexpr int T = 2048, Dh = 128, KV = 4, KB = 64, QKVW = 3072, KOFF = 2048;
  __shared__ char lds[65536];
  const int tid = threadIdx.x, lane = tid & 63, w = tid >> 6;
  const int hi = lane >> 5, lq = lane & 31;
  const int bx = blockIdx.x;
  // job table, descending duration: tiles = i1-i0 in {16,16,16,14,14,12,12,12,10,10,8,4}
  const int job = bx >> 6;
  const int jqt_[12] = {7, 7, 3, 6, 6, 5, 5, 2, 4, 4, 1, 0};
  const int ji0_[12] = {0, 16, 0, 0, 14, 0, 12, 0, 0, 10, 0, 0};
  const int ji1_[12] = {16, 32, 16, 14, 28, 12, 24, 12, 10, 20, 8, 4};
  const int jpp_[12] = {0, 1, -1, 0, 1, 0, 1, -1, 0, 1, -1, -1};
  const int qt = jqt_[job], i0 = ji0_[job], i1 = ji1_[job], jp = jpp_[job];
  const int b = (bx >> 4) & 3, h = bx & 15;
  const int kh = h >> 2;
  const int q0 = qt * 256 + w * 32;
  const int qg = q0 + lq;
  const int swz = (lane & 7) << 4;

  short8 aq[8];
  {
    const bf16* qp = qkv + ((size_t)(b * T + qg)) * QKVW + h * Dh + hi * 8;
#pragma unroll
    for (int m = 0; m < 8; ++m) aq[m] = *(const short8*)(qp + m * 16);
  }
  __builtin_amdgcn_s_waitcnt(0);

  // fused RoPE + RMS on Q; folds 1/sqrt(D) and log2(e)
  {
    float ss = 0.f;
#pragma unroll
    for (int m = 0; m < 8; ++m)
#pragma unroll
      for (int e = 0; e < 8; ++e) { float v = bf2f(aq[m][e]); ss += v * v; }
    ss += __shfl_xor(ss, 32, 64);
    float rn = rsqrtf(ss * (1.f / 128.f) + 1e-5f) * (0.08838834764831845f * 1.4426950408889634f);
    const float4* cq4 = (const float4*)(cosp + (size_t)qg * 64) + hi * 2;
    const float4* sq4 = (const float4*)(sinp + (size_t)qg * 64) + hi * 2;
#pragma unroll
    for (int m = 0; m < 4; ++m) {
      float4 c0 = cq4[m * 4], c1 = cq4[m * 4 + 1];
      float4 s0 = sq4[m * 4], s1 = sq4[m * 4 + 1];
      float cc[8] = {c0.x, c0.y, c0.z, c0.w, c1.x, c1.y, c1.z, c1.w};
      float sn[8] = {s0.x, s0.y, s0.z, s0.w, s1.x, s1.y, s1.z, s1.w};
      short8 xl = aq[m], xh = aq[m + 4], nl, nh;
#pragma unroll
      for (int e = 0; e < 8; ++e) {
        float x1 = bf2f(xl[e]), x2 = bf2f(xh[e]);
        nl[e] = bf_bits((x1 * cc[e] - x2 * sn[e]) * rn);
        nh[e] = bf_bits((x1 * sn[e] + x2 * cc[e]) * rn);
      }
      aq[m] = nl; aq[m + 4] = nh;
    }
  }

  f32x16 acc[4] = {};
  float mrow = -1e4f, lrow = 0.f;

  auto stage = [&](int buf, int kv0) {
#pragma unroll
    for (int p = 0; p < 2; ++p) {        // K: [64 kv][256B]
      int off = tid * 16 + p * 8192;
      int row = off >> 8, cb = off & 255;
      int scb = cb ^ ((row & 7) << 4);
      gload_lds16((const char*)qkv + (((size_t)(b * T + kv0 + row)) * QKVW + KOFF + kh * Dh) * 2 + scb,
                  lds + buf * 16384 + off);
    }
#pragma unroll
    for (int p = 0; p < 2; ++p) {        // V^T: [128 d][128B]
      int off = tid * 16 + p * 8192;
      int row = off >> 7, cb = off & 127;
      int scb = cb ^ ((row & 7) << 4);
      gload_lds16((const char*)vt + (((size_t)((b * KV + kh) * Dh + row)) * T + kv0) * 2 + scb,
                  lds + 32768 + buf * 16384 + off);
    }
  };

  const int lastit = (q0 + 31) >> 6;
  stage(0, i0 * KB);
  int cur = 0;

  for (int it = i0; it < i1; ++it) {
    asm volatile("s_waitcnt vmcnt(0)" ::: "memory");
    __builtin_amdgcn_s_barrier();
    if (it + 1 < i1) stage(cur ^ 1, (it + 1) * KB);
    if (it <= lastit) {
      const char* sK = lds + cur * 16384;
      const char* sV = lds + 32768 + cur * 16384;
      const int kv0 = it * KB;

      f32x16 s0 = {}, s1 = {};
      __builtin_amdgcn_s_setprio(1);
#pragma unroll
      for (int m = 0; m < 8; ++m) {
        short8 ak = *(const short8*)(sK + lq * 256 + ((m * 32 + hi * 16) ^ swz));
        s0 = MFMA32(ak, aq[m], s0);
      }
#pragma unroll
      for (int m = 0; m < 8; ++m) {
        short8 ak = *(const short8*)(sK + (32 + lq) * 256 + ((m * 32 + hi * 16) ^ swz));
        s1 = MFMA32(ak, aq[m], s1);
      }
      __builtin_amdgcn_s_setprio(0);

      if (kv0 + 63 > q0) {
#pragma unroll
        for (int r = 0; r < 16; ++r) {
          int krow = (r & 3) + 8 * (r >> 2) + 4 * hi;
          if (kv0 + krow > qg) s0[r] = -1e30f;
          if (kv0 + 32 + krow > qg) s1[r] = -1e30f;
        }
      }

      float mx[16];
#pragma unroll
      for (int r = 0; r < 16; ++r) mx[r] = fmaxf(s0[r], s1[r]);
#pragma unroll
      for (int st = 8; st > 0; st >>= 1)
#pragma unroll
        for (int r = 0; r < 16; ++r) if (r < st) mx[r] = fmaxf(mx[r], mx[r + st]);
      float tmax = fmaxf(mx[0], __shfl_xor(mx[0], 32, 64));
      if (!__all(tmax - mrow <= 11.5f)) {   // defer-max (T13), 8*log2e
        float mn = fmaxf(mrow, tmax);
        float corr = exp2g(mrow - mn);
        mrow = mn;
        lrow *= corr;
#pragma unroll
        for (int dt = 0; dt < 4; ++dt)
#pragma unroll
          for (int r = 0; r < 16; ++r) acc[dt][r] *= corr;
      }
      float sm[16];
#pragma unroll
      for (int r = 0; r < 16; ++r) {
        s0[r] = exp2g(s0[r] - mrow);
        s1[r] = exp2g(s1[r] - mrow);
        sm[r] = s0[r] + s1[r];
      }
#pragma unroll
      for (int st = 8; st > 0; st >>= 1)
#pragma unroll
        for (int r = 0; r < 16; ++r) if (r < st) sm[r] += sm[r + st];
      lrow += sm[0] + __shfl_xor(sm[0], 32, 64);

      unsigned int u[16];
#pragma unroll
      for (int g = 0; g < 4; ++g) {
        u[g * 2 + 0] = pk2(s0[4 * g + 0], s0[4 * g + 1]);
        u[g * 2 + 1] = pk2(s0[4 * g + 2], s0[4 * g + 3]);
        u[8 + g * 2 + 0] = pk2(s1[4 * g + 0], s1[4 * g + 1]);
        u[8 + g * 2 + 1] = pk2(s1[4 * g + 2], s1[4 * g + 3]);
      }
      short8 pb[4];
#pragma unroll
      for (int kvs = 0; kvs < 4; ++kvs) {
        unsigned int lo0 = u[4 * kvs + 0], lo1 = u[4 * kvs + 1];
        unsigned int hi0 = u[4 * kvs + 2], hi1 = u[4 * kvs + 3];
        asm volatile("v_permlane32_swap_b32 %0, %1" : "+v"(lo0), "+v"(hi0));
        asm volatile("v_permlane32_swap_b32 %0, %1" : "+v"(lo1), "+v"(hi1));
        union { short8 v; unsigned int q[4]; } P;
        P.q[0] = lo0; P.q[1] = lo1; P.q[2] = hi0; P.q[3] = hi1;
        pb[kvs] = P.v;
      }

      __builtin_amdgcn_s_setprio(1);
#pragma unroll
      for (int dt = 0; dt < 4; ++dt) {
#pragma unroll
        for (int kvs = 0; kvs < 4; ++kvs) {
          short8 av = *(const short8*)(sV + (dt * 32 + lq) * 128 + ((kvs * 32 + hi * 16) ^ swz));
          acc[dt] = MFMA32(av, pb[kvs], acc[dt]);
        }
      }
      __builtin_amdgcn_s_setprio(0);
    }
    cur ^= 1;
  }

  // ---- writeout: normalize+store y (direct) OR unnormalized partial + (m,l) ----
  const int tileIdx = ((b * 16 + h) * 4 + (7 - qt));   // valid for split jobs only
  float inv = (jp < 0) ? (1.f / lrow) : 1.0f;
  if (jp >= 0 && hi == 0) {
    pML[(tileIdx * 2 + jp) * 256 + w * 32 + lq] = make_float2(mrow, lrow);
  }
  __syncthreads();
  char* myO = lds + w * 8192;
#pragma unroll
  for (int dt = 0; dt < 4; ++dt)
#pragma unroll
    for (int i = 0; i < 8; ++i) {
      int d = ((2 * i) & 3) + 8 * (i >> 1) + 4 * hi;
      unsigned int pkd = pk2(acc[dt][2 * i] * inv, acc[dt][2 * i + 1] * inv);
      *(unsigned int*)(myO + lq * 256 + ((dt * 64 + d * 2) ^ ((lq & 7) << 4))) = pkd;
    }
  __syncthreads();
  if (jp < 0) {
    const int row0 = b * T + qt * 256;
#pragma unroll
    for (int p = 0; p < 8; ++p) {
      int off = (p * 512 + tid) * 16;
      int q = off >> 8, cb = off & 255;
      short8 v = *(const short8*)(lds + (q >> 5) * 8192 + (q & 31) * 256 + (cb ^ ((q & 7) << 4)));
      *(short8*)((char*)y + ((size_t)(row0 + q) * 2048 + h * 128) * 2 + cb) = v;
    }
  } else {
    char* pOt = (char*)pO + (size_t)(tileIdx * 2 + jp) * 65536;  // [256 rows][256 B]
#pragma unroll
    for (int p = 0; p < 8; ++p) {
      int off = (p * 512 + tid) * 16;
      int q = off >> 8, cb = off & 255;
      short8 v = *(const short8*)(lds + (q >> 5) * 8192 + (q & 31) * 256 + (cb ^ ((q & 7) << 4)));
      *(short8*)(pOt + off) = v;
    }
  }
}

// ---------------- combine partials: y[tile rows] = (a1*O1 + a2*O2) / (a1*l1 + a2*l2) ----------------
__global__ __launch_bounds__(256) void combine_k(const bf16* __restrict__ pO,
                                                 const float2* __restrict__ pML,
                                                 bf16* __restrict__ y) {
  constexpr int T = 2048;
  int tile = blockIdx.x;              // (b*16+h)*4 + qts, qts = 7-qt
  int qts = tile & 3, bh = tile >> 2;
  int b = bh >> 4, h = bh & 15;
  int qt = 7 - qts;
  int r = threadIdx.x;                // row 0..255
  float2 ml1 = pML[(tile * 2 + 0) * 256 + r];
  float2 ml2 = pML[(tile * 2 + 1) * 256 + r];
  float m = fmaxf(ml1.x, ml2.x);
  float a1 = exp2g(ml1.x - m), a2 = exp2g(ml2.x - m);
  float linv = 1.f / (ml1.y * a1 + ml2.y * a2);
  float s1 = a1 * linv, s2 = a2 * linv;
  const bf16* O1 = pO + ((size_t)(tile * 2 + 0) * 256 + r) * 128;
  const bf16* O2 = pO + ((size_t)(tile * 2 + 1) * 256 + r) * 128;
  bf16* yp = y + ((size_t)(b * T + qt * 256 + r)) * 2048 + h * 128;
#pragma unroll
  for (int d0 = 0; d0 < 128; d0 += 8) {
    short8 o1 = *(const short8*)(O1 + d0);
    short8 o2 = *(const short8*)(O2 + d0);
    short8 o;
#pragma unroll
    for (int e = 0; e < 8; ++e)
      o[e] = bf_bits(s1 * bf2f(o1[e]) + s2 * bf2f(o2[e]));
    *(short8*)(yp + d0) = o;
  }
}

// ---------------- launch ----------------
extern "C" void kernel_launch(void* const* d_in, const int* in_sizes, int n_in,
                              void* d_out, int out_size, void* d_ws, size_t ws_size,
                              hipStream_t stream) {
  const float* x    = (const float*)d_in[0];
  const float* cosp = (const float*)d_in[1];
  const float* sinp = (const float*)d_in[2];
  const float* wq   = (const float*)d_in[3];
  const float* wk   = (const float*)d_in[4];
  const float* wv   = (const float*)d_in[5];
  const float* wp   = (const float*)d_in[6];
  float* out = (float*)d_out;

  constexpr size_t Mtok = 8192;  // B*T
  constexpr int Cdim = 2048, HD = 2048, KVD = 512, QKVW = 3072;

  char* ws = (char*)d_ws;
  bf16* xb    = (bf16*)ws; ws += Mtok * Cdim * 2;
  bf16* wqkvT = (bf16*)ws; ws += (size_t)QKVW * Cdim * 2;  // rows: wq^T | wk^T | wv^T
  bf16* wpT   = (bf16*)ws; ws += (size_t)Cdim * HD * 2;
  bf16* qkv   = (bf16*)ws; ws += Mtok * QKVW * 2;
  bf16* vtb   = (bf16*)ws; ws += Mtok * KVD * 2;
  bf16* yb    = (bf16*)ws; ws += Mtok * HD * 2;
  bf16* pO    = (bf16*)ws; ws += (size_t)256 * 2 * 256 * 128 * 2;  // 33.5 MB partial O
  float2* pML = (float2*)ws; ws += (size_t)256 * 2 * 256 * 8;      // 1 MB partial (m,l)

  // fused prep: x conversion (8192 blocks) + 4 weight transposes (10240 blocks)
  prep_k<<<dim3(18432), 256, 0, stream>>>(x, xb, wq, wk, wv, wp, wqkvT, wpT);

  // Q projection: 256 tiles = exact 1-round packing
  gemm256<bf16><<<dim3(256), 512, 0, stream>>>(xb, wqkvT, qkv, Cdim, 8, QKVW);
  // KV projection + fused K-rope/RMS + V-transpose
  gemm_kv<<<dim3(512), 256, 0, stream>>>(xb, wqkvT + (size_t)2048 * Cdim, qkv, vtb, cosp, sinp);

  // attention: 768 balanced jobs (heavy q-tiles kv-split) + partial combine
  attn_k<<<dim3(768), 512, 0, stream>>>(qkv, vtb, yb, pO, pML, cosp, sinp);
  combine_k<<<dim3(256), 256, 0, stream>>>(pO, pML, yb);

  gemm256<float><<<dim3(256), 512, 0, stream>>>(yb, wpT, out, Cdim, 8, 2048);
}

// Round 17
// 304.189 us; speedup vs baseline: 1.1157x; 1.1157x over previous
//
#include <hip/hip_runtime.h>
#include <hip/hip_bf16.h>
#include <stdint.h>

using bf16 = __hip_bfloat16;
typedef __attribute__((ext_vector_type(8))) short short8;
typedef __attribute__((ext_vector_type(4))) float f32x4;
typedef __attribute__((ext_vector_type(16))) float f32x16;

#define MFMA16(a,b,c) __builtin_amdgcn_mfma_f32_16x16x32_bf16(a,b,c,0,0,0)
#define MFMA32(a,b,c) __builtin_amdgcn_mfma_f32_32x32x16_bf16(a,b,c,0,0,0)

__device__ __forceinline__ void gload_lds16(const void* g, void* l) {
  __builtin_amdgcn_global_load_lds((const __attribute__((address_space(1))) void*)g,
                                   (__attribute__((address_space(3))) void*)l, 16, 0, 0);
}

__device__ __forceinline__ short bf_bits(float f) {
  bf16 h = __float2bfloat16(f);
  return *reinterpret_cast<short*>(&h);
}
// hardware packed f32->bf16 (RNE), low = a, high = b  [T12]
__device__ __forceinline__ unsigned int pk2(float a, float b) {
  unsigned int r;
  asm("v_cvt_pk_bf16_f32 %0, %1, %2" : "=v"(r) : "v"(a), "v"(b));
  return r;
}
__device__ __forceinline__ float bf2f(short s) {
  return __uint_as_float((unsigned int)(unsigned short)s << 16);
}
__device__ __forceinline__ float exp2g(float x) { return __builtin_amdgcn_exp2f(x); }

// ---------------- fused prep: x f32->bf16 (blocks 0..8191) + 4 weight transposes ----------------
__global__ __launch_bounds__(256) void prep_k(const float* __restrict__ x, bf16* __restrict__ xb,
                                              const float* __restrict__ wq, const float* __restrict__ wk,
                                              const float* __restrict__ wv, const float* __restrict__ wp,
                                              bf16* __restrict__ wqkvT, bf16* __restrict__ wpT) {
  __shared__ float tile[32][33];
  int bid = blockIdx.x;
  if (bid < 8192) {  // x conversion, 8 elems/thread
    size_t i = ((size_t)bid * 256 + threadIdx.x) * 8;
    float4 a = *(const float4*)(x + i);
    float4 b = *(const float4*)(x + i + 4);
    short8 pk;
    pk[0] = bf_bits(a.x); pk[1] = bf_bits(a.y); pk[2] = bf_bits(a.z); pk[3] = bf_bits(a.w);
    pk[4] = bf_bits(b.x); pk[5] = bf_bits(b.y); pk[6] = bf_bits(b.z); pk[7] = bf_bits(b.w);
    *(short8*)(xb + i) = pk;
    return;
  }
  bid -= 8192;
  const float* in; bf16* out; int N, loc;
  constexpr int K = 2048;
  if (bid < 4096)      { in = wq; out = wqkvT;                        N = 2048; loc = bid; }
  else if (bid < 5120) { in = wk; out = wqkvT + (size_t)2048 * K;     N = 512;  loc = bid - 4096; }
  else if (bid < 6144) { in = wv; out = wqkvT + (size_t)2560 * K;     N = 512;  loc = bid - 5120; }
  else                 { in = wp; out = wpT;                          N = 2048; loc = bid - 6144; }
  int nb = N >> 5;
  int n0 = (loc % nb) * 32, k0 = (loc / nb) * 32;
  int tx = threadIdx.x & 31, ty = threadIdx.x >> 5;  // 32 x 8
#pragma unroll
  for (int j = 0; j < 4; ++j) {
    int kk = ty + j * 8;
    tile[kk][tx] = in[(size_t)(k0 + kk) * N + n0 + tx];
  }
  __syncthreads();
#pragma unroll
  for (int j = 0; j < 4; ++j) {
    int nn = ty + j * 8;
    out[(size_t)(n0 + nn) * K + k0 + tx] = __float2bfloat16(tile[tx][nn]);
  }
}

// ---------------- 256x256 8-phase bf16 GEMM: C[.][ldC] = A[M][K] * Bt[N][K]^T ----------------
#define PHASE(buf, i0, ...)                                                       \
  {                                                                               \
    short8 a00 = ldA(buf, i0, 0), a01 = ldA(buf, i0, 1);                          \
    short8 a10 = ldA(buf, (i0) + 1, 0), a11 = ldA(buf, (i0) + 1, 1);              \
    __VA_ARGS__;                                                                  \
    __builtin_amdgcn_s_barrier();                                                 \
    asm volatile("s_waitcnt lgkmcnt(0)" ::: "memory");                            \
    __builtin_amdgcn_s_setprio(1);                                                \
    _Pragma("unroll") for (int j = 0; j < 4; ++j) {                               \
      acc[i0][j] = MFMA16(a00, bf_[2 * j], acc[i0][j]);                           \
      acc[i0][j] = MFMA16(a01, bf_[2 * j + 1], acc[i0][j]);                       \
      acc[(i0) + 1][j] = MFMA16(a10, bf_[2 * j], acc[(i0) + 1][j]);               \
      acc[(i0) + 1][j] = MFMA16(a11, bf_[2 * j + 1], acc[(i0) + 1][j]);           \
    }                                                                             \
    __builtin_amdgcn_s_setprio(0);                                                \
  }
#define LOADB(buf)                                                                \
  _Pragma("unroll") for (int j = 0; j < 4; ++j) {                                 \
    bf_[2 * j] = ldB(buf, j, 0);                                                  \
    bf_[2 * j + 1] = ldB(buf, j, 1);                                              \
  }
#define BAR __builtin_amdgcn_s_barrier()

template <typename OutT>
__global__ __launch_bounds__(512, 2) void gemm256(const bf16* __restrict__ A,
                                                  const bf16* __restrict__ Bt,
                                                  OutT* __restrict__ C, int K,
                                                  int NT, int ldC) {
  __shared__ char lds[131072];
  const int tid = threadIdx.x, lane = tid & 63, w = tid >> 6;
  const int wm = w >> 2, wn = w & 3;
  const int bx = blockIdx.x;
  const int chunk = gridDim.x >> 3;
  const int wgid = (bx & 7) * chunk + (bx >> 3);   // XCD-bijective (grid % 8 == 0)
  const int m0 = (wgid / NT) * 256, n0 = (wgid % NT) * 256;
  const int lm = lane & 15;
  const int sw = (lane & 7) << 4;
  const int g16 = (lane >> 4) << 4;
  const size_t strideAB = (size_t)K * 2;  // bytes per row

  auto stageA = [&](int buf, int h, int t) {
#pragma unroll
    for (int p2 = 0; p2 < 2; ++p2) {
      int off = tid * 16 + p2 * 8192;
      int row = off >> 7, cb = off & 127;
      int scb = cb ^ ((row & 7) << 4);
      gload_lds16((const char*)A + (size_t)(m0 + h * 128 + row) * strideAB + t * 128 + scb,
                  lds + buf * 65536 + h * 16384 + off);
    }
  };
  auto stageB = [&](int buf, int h, int t) {
#pragma unroll
    for (int p2 = 0; p2 < 2; ++p2) {
      int off = tid * 16 + p2 * 8192;
      int row = off >> 7, cb = off & 127;
      int scb = cb ^ ((row & 7) << 4);
      gload_lds16((const char*)Bt + (size_t)(n0 + h * 128 + row) * strideAB + t * 128 + scb,
                  lds + buf * 65536 + 32768 + h * 16384 + off);
    }
  };
  auto ldA = [&](int buf, int i, int ks) {
    int row = wm * 128 + i * 16 + lm;
    return *(const short8*)(lds + buf * 65536 + row * 128 + ((ks * 64 + g16) ^ sw));
  };
  auto ldB = [&](int buf, int j, int ks) {
    int row = wn * 64 + j * 16 + lm;
    return *(const short8*)(lds + buf * 65536 + 32768 + row * 128 + ((ks * 64 + g16) ^ sw));
  };

  f32x4 acc[8][4] = {};
  short8 bf_[8];
  const int niter = K / 128;

  stageA(0, 0, 0); stageA(0, 1, 0); stageB(0, 0, 0); stageB(0, 1, 0);
  stageB(1, 0, 1); stageB(1, 1, 1);
  asm volatile("s_waitcnt vmcnt(4)" ::: "memory");
  BAR;

  for (int i = 0; i < niter; ++i) {
    const int t0 = 2 * i, t1 = 2 * i + 1;
    const bool nl = (i + 1 < niter);
    LOADB(0);
    PHASE(0, 0, stageA(1, 0, t1)); BAR;
    PHASE(0, 2, stageA(1, 1, t1)); BAR;
    PHASE(0, 4, if (nl) stageB(0, 0, t0 + 2)); BAR;
    PHASE(0, 6, if (nl) stageB(0, 1, t0 + 2));
    if (nl) { asm volatile("s_waitcnt vmcnt(4)" ::: "memory"); }
    else    { asm volatile("s_waitcnt vmcnt(0)" ::: "memory"); }
    BAR;
    LOADB(1);
    PHASE(1, 0, if (nl) stageA(0, 0, t0 + 2)); BAR;
    PHASE(1, 2, if (nl) stageA(0, 1, t0 + 2)); BAR;
    PHASE(1, 4, if (nl) stageB(1, 0, t1 + 2)); BAR;
    PHASE(1, 6, if (nl) stageB(1, 1, t1 + 2));
    if (nl) { asm volatile("s_waitcnt vmcnt(4)" ::: "memory"); }
    BAR;
  }

  if constexpr (sizeof(OutT) == 2) {
    __syncthreads();
    bf16* sC = (bf16*)lds;
#pragma unroll
    for (int i = 0; i < 8; ++i) {
      int row = wm * 128 + i * 16 + (lane >> 4) * 4;
#pragma unroll
      for (int j = 0; j < 4; ++j) {
        int col = wn * 64 + j * 16 + lm;
#pragma unroll
        for (int r = 0; r < 4; ++r) sC[(row + r) * 256 + col] = __float2bfloat16(acc[i][j][r]);
      }
    }
    __syncthreads();
#pragma unroll
    for (int p = 0; p < 16; ++p) {
      int off = tid * 16 + p * 8192;
      int row = off >> 9, cb = off & 511;
      *(short8*)((char*)C + ((size_t)(m0 + row) * ldC + n0) * 2 + cb) =
          *(const short8*)(lds + off);
    }
  } else {
    // f32 epilogue: LDS-staged in two 128-row halves, coalesced 16B stores
    float* sCf = (float*)lds;
#pragma unroll
    for (int half = 0; half < 2; ++half) {
      __syncthreads();
      if (wm == half) {
#pragma unroll
        for (int i = 0; i < 8; ++i) {
          int row = i * 16 + (lane >> 4) * 4;   // local 0..127
#pragma unroll
          for (int j = 0; j < 4; ++j) {
            int col = wn * 64 + j * 16 + lm;
#pragma unroll
            for (int r = 0; r < 4; ++r) sCf[(row + r) * 256 + col] = acc[i][j][r];
          }
        }
      }
      __syncthreads();
#pragma unroll
      for (int p = 0; p < 16; ++p) {
        int off = tid * 16 + p * 8192;          // 0..131071 bytes
        int row = off >> 10, cb = off & 1023;   // 1024 B per 256-f32 row
        *(f32x4*)((char*)C + ((size_t)(m0 + half * 128 + row) * ldC + n0) * 4 + cb) =
            *(const f32x4*)(lds + off);
      }
    }
  }
}

// ---------------- KV projection GEMM (128x128, m97 structure) + fused epilogue ----------------
__global__ __launch_bounds__(256) void gemm_kv(const bf16* __restrict__ A,
                                               const bf16* __restrict__ Bt,
                                               bf16* __restrict__ qkv,
                                               bf16* __restrict__ vtb,
                                               const float* __restrict__ cosp,
                                               const float* __restrict__ sinp) {
  constexpr int BM = 128, BN = 128, BK = 64, K = 2048, QKVW = 3072, T = 2048, SCP = 132;
  __shared__ char smem[BM * SCP * 2];
  bf16* sA = (bf16*)smem;
  bf16* sB = (bf16*)(smem + 16384);
  int tid = threadIdx.x;
  int lane = tid & 63, w = tid >> 6;
  int flat = blockIdx.x;
  int wgid = (flat & 7) * (gridDim.x >> 3) + (flat >> 3);
  int m0 = (wgid >> 3) * BM, n0 = (wgid & 7) * BN;
  int wm = (w >> 1) * 64, wn = (w & 1) * 64;
  f32x4 acc[4][4] = {};
  for (int kt = 0; kt < K / BK; ++kt) {
    __syncthreads();
    int kb = kt * BK;
#pragma unroll
    for (int it = 0; it < 4; ++it) {
      int off = tid * 16 + it * 4096;
      int row = off >> 7, cb = off & 127;
      gload_lds16((const char*)A + (((size_t)(m0 + row)) * K + kb) * 2 + cb, (char*)sA + off);
    }
#pragma unroll
    for (int it = 0; it < 4; ++it) {
      int off = tid * 16 + it * 4096;
      int row = off >> 7, cb = off & 127;
      gload_lds16((const char*)Bt + (((size_t)(n0 + row)) * K + kb) * 2 + cb, (char*)sB + off);
    }
    asm volatile("s_waitcnt vmcnt(0)" ::: "memory");
    __syncthreads();
#pragma unroll
    for (int ks = 0; ks < 2; ++ks) {
      short8 af[4], bfr[4];
#pragma unroll
      for (int i = 0; i < 4; ++i) {
        af[i]  = *(const short8*)(sA + (wm + i * 16 + (lane & 15)) * BK + ks * 32 + (lane >> 4) * 8);
        bfr[i] = *(const short8*)(sB + (wn + i * 16 + (lane & 15)) * BK + ks * 32 + (lane >> 4) * 8);
      }
#pragma unroll
      for (int i = 0; i < 4; ++i)
#pragma unroll
        for (int j = 0; j < 4; ++j)
          acc[i][j] = MFMA16(af[i], bfr[j], acc[i][j]);
    }
  }

  const int kvh = (n0 >> 7) & 3;
  const int b = m0 >> 11, t0 = m0 & (T - 1);
  bf16* sC = (bf16*)smem;
  __syncthreads();
  if (n0 >= 512) {
    // V tile: transposed store sC_T[d][t_local], then coalesced to vt
#pragma unroll
    for (int i = 0; i < 4; ++i) {
      int row = wm + i * 16 + (lane >> 4) * 4;
#pragma unroll
      for (int j = 0; j < 4; ++j) {
        int col = wn + j * 16 + (lane & 15);
#pragma unroll
        for (int r = 0; r < 4; ++r) sC[col * SCP + row + r] = __float2bfloat16(acc[i][j][r]);
      }
    }
    __syncthreads();
#pragma unroll
    for (int p = 0; p < 8; ++p) {
      int g = p * 2048 + tid * 8;
      int d = g >> 7, tb = g & 127;
      *(short8*)(vtb + ((size_t)((b * 4 + kvh) * 128 + d)) * T + t0 + tb) =
          *(const short8*)(sC + d * SCP + tb);
    }
  } else {
    // K tile: rope+RMS in LDS, linear store
#pragma unroll
    for (int i = 0; i < 4; ++i) {
      int row = wm + i * 16 + (lane >> 4) * 4;
#pragma unroll
      for (int j = 0; j < 4; ++j) {
        int col = wn + j * 16 + (lane & 15);
#pragma unroll
        for (int r = 0; r < 4; ++r) sC[(row + r) * SCP + col] = __float2bfloat16(acc[i][j][r]);
      }
    }
    __syncthreads();
    for (int rr = 0; rr < 32; ++rr) {
      int row = w * 32 + rr;
      int t = t0 + row;
      float x1 = __bfloat162float(sC[row * SCP + lane]);
      float x2 = __bfloat162float(sC[row * SCP + lane + 64]);
      float c = cosp[t * 64 + lane], s = sinp[t * 64 + lane];
      float o1 = x1 * c - x2 * s;
      float o2 = x1 * s + x2 * c;
      float ss = o1 * o1 + o2 * o2;
#pragma unroll
      for (int m = 1; m < 64; m <<= 1) ss += __shfl_xor(ss, m, 64);
      float r = rsqrtf(ss * (1.f / 128.f) + 1e-5f);
      sC[row * SCP + lane] = __float2bfloat16(o1 * r);
      sC[row * SCP + lane + 64] = __float2bfloat16(o2 * r);
    }
    __syncthreads();
#pragma unroll
    for (int p = 0; p < 8; ++p) {
      int g = p * 2048 + tid * 8;
      int row = g >> 7, cb = g & 127;
      *(short8*)(qkv + (size_t)(m0 + row) * QKVW + 2048 + kvh * 128 + cb) =
          *(const short8*)(sC + row * SCP + cb);
    }
  }
}

// ---------------- flash attention: 8-wave 32x32 swapped-QK^T + fused Q-RoPE/RMS ----------------
// Single barrier per KV-tile: vmcnt(0) -> barrier -> stage(next) -> compute.
__global__ __launch_bounds__(512, 2) void attn_k(const bf16* __restrict__ qkv,
                                                 const bf16* __restrict__ vt,
                                                 bf16* __restrict__ y,
                                                 const float* __restrict__ cosp,
                                                 const float* __restrict__ sinp) {
  constexpr int T = 2048, Dh = 128, KV = 4, KB = 64, QKVW = 3072, KOFF = 2048;
  __shared__ char lds[65536];
  const int tid = threadIdx.x, lane = tid & 63, w = tid >> 6;
  const int hi = lane >> 5, lq = lane & 31;
  const int bx = blockIdx.x;
  const int qt = 7 - (bx >> 6);          // longest blocks dispatch first
  const int b = (bx >> 4) & 3, h = bx & 15;
  const int kh = h >> 2;
  const int q0 = qt * 256 + w * 32;
  const int qg = q0 + lq;
  const int swz = (lane & 7) << 4;

  short8 aq[8];
  {
    const bf16* qp = qkv + ((size_t)(b * T + qg)) * QKVW + h * Dh + hi * 8;
#pragma unroll
    for (int m = 0; m < 8; ++m) aq[m] = *(const short8*)(qp + m * 16);
  }
  __builtin_amdgcn_s_waitcnt(0);

  // fused RoPE + RMS on Q; folds 1/sqrt(D) and log2(e)
  {
    float ss = 0.f;
#pragma unroll
    for (int m = 0; m < 8; ++m)
#pragma unroll
      for (int e = 0; e < 8; ++e) { float v = bf2f(aq[m][e]); ss += v * v; }
    ss += __shfl_xor(ss, 32, 64);
    float rn = rsqrtf(ss * (1.f / 128.f) + 1e-5f) * (0.08838834764831845f * 1.4426950408889634f);
    const float4* cq4 = (const float4*)(cosp + (size_t)qg * 64) + hi * 2;
    const float4* sq4 = (const float4*)(sinp + (size_t)qg * 64) + hi * 2;
#pragma unroll
    for (int m = 0; m < 4; ++m) {
      float4 c0 = cq4[m * 4], c1 = cq4[m * 4 + 1];
      float4 s0 = sq4[m * 4], s1 = sq4[m * 4 + 1];
      float cc[8] = {c0.x, c0.y, c0.z, c0.w, c1.x, c1.y, c1.z, c1.w};
      float sn[8] = {s0.x, s0.y, s0.z, s0.w, s1.x, s1.y, s1.z, s1.w};
      short8 xl = aq[m], xh = aq[m + 4], nl, nh;
#pragma unroll
      for (int e = 0; e < 8; ++e) {
        float x1 = bf2f(xl[e]), x2 = bf2f(xh[e]);
        nl[e] = bf_bits((x1 * cc[e] - x2 * sn[e]) * rn);
        nh[e] = bf_bits((x1 * sn[e] + x2 * cc[e]) * rn);
      }
      aq[m] = nl; aq[m + 4] = nh;
    }
  }

  f32x16 acc[4] = {};
  float mrow = -1e4f, lrow = 0.f;

  auto stage = [&](int buf, int kv0) {
#pragma unroll
    for (int p = 0; p < 2; ++p) {        // K: [64 kv][256B]
      int off = tid * 16 + p * 8192;
      int row = off >> 8, cb = off & 255;
      int scb = cb ^ ((row & 7) << 4);
      gload_lds16((const char*)qkv + (((size_t)(b * T + kv0 + row)) * QKVW + KOFF + kh * Dh) * 2 + scb,
                  lds + buf * 16384 + off);
    }
#pragma unroll
    for (int p = 0; p < 2; ++p) {        // V^T: [128 d][128B]
      int off = tid * 16 + p * 8192;
      int row = off >> 7, cb = off & 127;
      int scb = cb ^ ((row & 7) << 4);
      gload_lds16((const char*)vt + (((size_t)((b * KV + kh) * Dh + row)) * T + kv0) * 2 + scb,
                  lds + 32768 + buf * 16384 + off);
    }
  };

  const int nt = (qt + 1) * 4;
  const int lastit = (q0 + 31) >> 6;
  stage(0, 0);
  int cur = 0;

  for (int it = 0; it < nt; ++it) {
    asm volatile("s_waitcnt vmcnt(0)" ::: "memory");
    __builtin_amdgcn_s_barrier();
    if (it + 1 < nt) stage(cur ^ 1, (it + 1) * KB);
    if (it <= lastit) {
      const char* sK = lds + cur * 16384;
      const char* sV = lds + 32768 + cur * 16384;
      const int kv0 = it * KB;

      f32x16 s0 = {}, s1 = {};
      __builtin_amdgcn_s_setprio(1);
#pragma unroll
      for (int m = 0; m < 8; ++m) {
        short8 ak = *(const short8*)(sK + lq * 256 + ((m * 32 + hi * 16) ^ swz));
        s0 = MFMA32(ak, aq[m], s0);
      }
#pragma unroll
      for (int m = 0; m < 8; ++m) {
        short8 ak = *(const short8*)(sK + (32 + lq) * 256 + ((m * 32 + hi * 16) ^ swz));
        s1 = MFMA32(ak, aq[m], s1);
      }
      __builtin_amdgcn_s_setprio(0);

      if (kv0 + 63 > q0) {
#pragma unroll
        for (int r = 0; r < 16; ++r) {
          int krow = (r & 3) + 8 * (r >> 2) + 4 * hi;
          if (kv0 + krow > qg) s0[r] = -1e30f;
          if (kv0 + 32 + krow > qg) s1[r] = -1e30f;
        }
      }

      float mx[16];
#pragma unroll
      for (int r = 0; r < 16; ++r) mx[r] = fmaxf(s0[r], s1[r]);
#pragma unroll
      for (int st = 8; st > 0; st >>= 1)
#pragma unroll
        for (int r = 0; r < 16; ++r) if (r < st) mx[r] = fmaxf(mx[r], mx[r + st]);
      float tmax = fmaxf(mx[0], __shfl_xor(mx[0], 32, 64));
      if (!__all(tmax - mrow <= 11.5f)) {   // defer-max (T13), 8*log2e
        float mn = fmaxf(mrow, tmax);
        float corr = exp2g(mrow - mn);
        mrow = mn;
        lrow *= corr;
#pragma unroll
        for (int dt = 0; dt < 4; ++dt)
#pragma unroll
          for (int r = 0; r < 16; ++r) acc[dt][r] *= corr;
      }
      float sm[16];
#pragma unroll
      for (int r = 0; r < 16; ++r) {
        s0[r] = exp2g(s0[r] - mrow);
        s1[r] = exp2g(s1[r] - mrow);
        sm[r] = s0[r] + s1[r];
      }
#pragma unroll
      for (int st = 8; st > 0; st >>= 1)
#pragma unroll
        for (int r = 0; r < 16; ++r) if (r < st) sm[r] += sm[r + st];
      lrow += sm[0] + __shfl_xor(sm[0], 32, 64);

      unsigned int u[16];
#pragma unroll
      for (int g = 0; g < 4; ++g) {
        u[g * 2 + 0] = pk2(s0[4 * g + 0], s0[4 * g + 1]);
        u[g * 2 + 1] = pk2(s0[4 * g + 2], s0[4 * g + 3]);
        u[8 + g * 2 + 0] = pk2(s1[4 * g + 0], s1[4 * g + 1]);
        u[8 + g * 2 + 1] = pk2(s1[4 * g + 2], s1[4 * g + 3]);
      }
      short8 pb[4];
#pragma unroll
      for (int kvs = 0; kvs < 4; ++kvs) {
        unsigned int lo0 = u[4 * kvs + 0], lo1 = u[4 * kvs + 1];
        unsigned int hi0 = u[4 * kvs + 2], hi1 = u[4 * kvs + 3];
        asm volatile("v_permlane32_swap_b32 %0, %1" : "+v"(lo0), "+v"(hi0));
        asm volatile("v_permlane32_swap_b32 %0, %1" : "+v"(lo1), "+v"(hi1));
        union { short8 v; unsigned int q[4]; } P;
        P.q[0] = lo0; P.q[1] = lo1; P.q[2] = hi0; P.q[3] = hi1;
        pb[kvs] = P.v;
      }

      __builtin_amdgcn_s_setprio(1);
#pragma unroll
      for (int dt = 0; dt < 4; ++dt) {
#pragma unroll
        for (int kvs = 0; kvs < 4; ++kvs) {
          short8 av = *(const short8*)(sV + (dt * 32 + lq) * 128 + ((kvs * 32 + hi * 16) ^ swz));
          acc[dt] = MFMA32(av, pb[kvs], acc[dt]);
        }
      }
      __builtin_amdgcn_s_setprio(0);
    }
    cur ^= 1;
  }

  float inv = 1.f / lrow;
  __syncthreads();
  char* myO = lds + w * 8192;
#pragma unroll
  for (int dt = 0; dt < 4; ++dt)
#pragma unroll
    for (int i = 0; i < 8; ++i) {
      int d = ((2 * i) & 3) + 8 * (i >> 1) + 4 * hi;
      unsigned int pkd = pk2(acc[dt][2 * i] * inv, acc[dt][2 * i + 1] * inv);
      *(unsigned int*)(myO + lq * 256 + ((dt * 64 + d * 2) ^ ((lq & 7) << 4))) = pkd;
    }
  __syncthreads();
  const int row0 = b * T + qt * 256;
#pragma unroll
  for (int p = 0; p < 8; ++p) {
    int off = (p * 512 + tid) * 16;
    int q = off >> 8, cb = off & 255;
    short8 v = *(const short8*)(lds + (q >> 5) * 8192 + (q & 31) * 256 + (cb ^ ((q & 7) << 4)));
    *(short8*)((char*)y + ((size_t)(row0 + q) * 2048 + h * 128) * 2 + cb) = v;
  }
}

// ---------------- launch ----------------
extern "C" void kernel_launch(void* const* d_in, const int* in_sizes, int n_in,
                              void* d_out, int out_size, void* d_ws, size_t ws_size,
                              hipStream_t stream) {
  const float* x    = (const float*)d_in[0];
  const float* cosp = (const float*)d_in[1];
  const float* sinp = (const float*)d_in[2];
  const float* wq   = (const float*)d_in[3];
  const float* wk   = (const float*)d_in[4];
  const float* wv   = (const float*)d_in[5];
  const float* wp   = (const float*)d_in[6];
  float* out = (float*)d_out;

  constexpr size_t Mtok = 8192;  // B*T
  constexpr int Cdim = 2048, HD = 2048, KVD = 512, QKVW = 3072;

  char* ws = (char*)d_ws;
  bf16* xb    = (bf16*)ws; ws += Mtok * Cdim * 2;
  bf16* wqkvT = (bf16*)ws; ws += (size_t)QKVW * Cdim * 2;  // rows: wq^T | wk^T | wv^T
  bf16* wpT   = (bf16*)ws; ws += (size_t)Cdim * HD * 2;
  bf16* qkv   = (bf16*)ws; ws += Mtok * QKVW * 2;
  bf16* vtb   = (bf16*)ws; ws += Mtok * KVD * 2;
  bf16* yb    = (bf16*)ws; ws += Mtok * HD * 2;

  // fused prep: x conversion (8192 blocks) + 4 weight transposes (10240 blocks)
  prep_k<<<dim3(18432), 256, 0, stream>>>(x, xb, wq, wk, wv, wp, wqkvT, wpT);

  // Q projection: 256 tiles = exact 1-round packing
  gemm256<bf16><<<dim3(256), 512, 0, stream>>>(xb, wqkvT, qkv, Cdim, 8, QKVW);
  // KV projection + fused K-rope/RMS + V-transpose
  gemm_kv<<<dim3(512), 256, 0, stream>>>(xb, wqkvT + (size_t)2048 * Cdim, qkv, vtb, cosp, sinp);

  attn_k<<<dim3(512), 512, 0, stream>>>(qkv, vtb, yb, cosp, sinp);

  gemm256<float><<<dim3(256), 512, 0, stream>>>(yb, wpT, out, Cdim, 8, 2048);
}

// Round 18
// 302.488 us; speedup vs baseline: 1.1220x; 1.0056x over previous
//
#include <hip/hip_runtime.h>
#include <hip/hip_bf16.h>
#include <stdint.h>

using bf16 = __hip_bfloat16;
typedef __attribute__((ext_vector_type(8))) short short8;
typedef __attribute__((ext_vector_type(4))) float f32x4;
typedef __attribute__((ext_vector_type(16))) float f32x16;

#define MFMA16(a,b,c) __builtin_amdgcn_mfma_f32_16x16x32_bf16(a,b,c,0,0,0)
#define MFMA32(a,b,c) __builtin_amdgcn_mfma_f32_32x32x16_bf16(a,b,c,0,0,0)

__device__ __forceinline__ void gload_lds16(const void* g, void* l) {
  __builtin_amdgcn_global_load_lds((const __attribute__((address_space(1))) void*)g,
                                   (__attribute__((address_space(3))) void*)l, 16, 0, 0);
}

__device__ __forceinline__ short bf_bits(float f) {
  bf16 h = __float2bfloat16(f);
  return *reinterpret_cast<short*>(&h);
}
// hardware packed f32->bf16 (RNE), low = a, high = b  [T12]
__device__ __forceinline__ unsigned int pk2(float a, float b) {
  unsigned int r;
  asm("v_cvt_pk_bf16_f32 %0, %1, %2" : "=v"(r) : "v"(a), "v"(b));
  return r;
}
__device__ __forceinline__ float bf2f(short s) {
  return __uint_as_float((unsigned int)(unsigned short)s << 16);
}
__device__ __forceinline__ float exp2g(float x) { return __builtin_amdgcn_exp2f(x); }

// ---------------- fused prep: x f32->bf16 (blocks 0..8191) + 4 weight transposes ----------------
__global__ __launch_bounds__(256) void prep_k(const float* __restrict__ x, bf16* __restrict__ xb,
                                              const float* __restrict__ wq, const float* __restrict__ wk,
                                              const float* __restrict__ wv, const float* __restrict__ wp,
                                              bf16* __restrict__ wqkvT, bf16* __restrict__ wpT) {
  __shared__ float tile[32][33];
  int bid = blockIdx.x;
  if (bid < 8192) {  // x conversion, 8 elems/thread
    size_t i = ((size_t)bid * 256 + threadIdx.x) * 8;
    float4 a = *(const float4*)(x + i);
    float4 b = *(const float4*)(x + i + 4);
    short8 pk;
    pk[0] = bf_bits(a.x); pk[1] = bf_bits(a.y); pk[2] = bf_bits(a.z); pk[3] = bf_bits(a.w);
    pk[4] = bf_bits(b.x); pk[5] = bf_bits(b.y); pk[6] = bf_bits(b.z); pk[7] = bf_bits(b.w);
    *(short8*)(xb + i) = pk;
    return;
  }
  bid -= 8192;
  const float* in; bf16* out; int N, loc;
  constexpr int K = 2048;
  if (bid < 4096)      { in = wq; out = wqkvT;                        N = 2048; loc = bid; }
  else if (bid < 5120) { in = wk; out = wqkvT + (size_t)2048 * K;     N = 512;  loc = bid - 4096; }
  else if (bid < 6144) { in = wv; out = wqkvT + (size_t)2560 * K;     N = 512;  loc = bid - 5120; }
  else                 { in = wp; out = wpT;                          N = 2048; loc = bid - 6144; }
  int nb = N >> 5;
  int n0 = (loc % nb) * 32, k0 = (loc / nb) * 32;
  int tx = threadIdx.x & 31, ty = threadIdx.x >> 5;  // 32 x 8
#pragma unroll
  for (int j = 0; j < 4; ++j) {
    int kk = ty + j * 8;
    tile[kk][tx] = in[(size_t)(k0 + kk) * N + n0 + tx];
  }
  __syncthreads();
#pragma unroll
  for (int j = 0; j < 4; ++j) {
    int nn = ty + j * 8;
    out[(size_t)(n0 + nn) * K + k0 + tx] = __float2bfloat16(tile[tx][nn]);
  }
}

// ---------------- 256x256 8-phase bf16 GEMM: C[.][ldC] = A[M][K] * Bt[N][K]^T ----------------
#define PHASE(buf, i0, ...)                                                       \
  {                                                                               \
    short8 a00 = ldA(buf, i0, 0), a01 = ldA(buf, i0, 1);                          \
    short8 a10 = ldA(buf, (i0) + 1, 0), a11 = ldA(buf, (i0) + 1, 1);              \
    __VA_ARGS__;                                                                  \
    __builtin_amdgcn_s_barrier();                                                 \
    asm volatile("s_waitcnt lgkmcnt(0)" ::: "memory");                            \
    __builtin_amdgcn_s_setprio(1);                                                \
    _Pragma("unroll") for (int j = 0; j < 4; ++j) {                               \
      acc[i0][j] = MFMA16(a00, bf_[2 * j], acc[i0][j]);                           \
      acc[i0][j] = MFMA16(a01, bf_[2 * j + 1], acc[i0][j]);                       \
      acc[(i0) + 1][j] = MFMA16(a10, bf_[2 * j], acc[(i0) + 1][j]);               \
      acc[(i0) + 1][j] = MFMA16(a11, bf_[2 * j + 1], acc[(i0) + 1][j]);           \
    }                                                                             \
    __builtin_amdgcn_s_setprio(0);                                                \
  }
#define LOADB(buf)                                                                \
  _Pragma("unroll") for (int j = 0; j < 4; ++j) {                                 \
    bf_[2 * j] = ldB(buf, j, 0);                                                  \
    bf_[2 * j + 1] = ldB(buf, j, 1);                                              \
  }
#define BAR __builtin_amdgcn_s_barrier()

template <typename OutT>
__global__ __launch_bounds__(512, 2) void gemm256(const bf16* __restrict__ A,
                                                  const bf16* __restrict__ Bt,
                                                  OutT* __restrict__ C, int K,
                                                  int NT, int ldC) {
  __shared__ char lds[131072];
  const int tid = threadIdx.x, lane = tid & 63, w = tid >> 6;
  const int wm = w >> 2, wn = w & 3;
  const int bx = blockIdx.x;
  const int chunk = gridDim.x >> 3;
  const int wgid = (bx & 7) * chunk + (bx >> 3);   // XCD-bijective (grid % 8 == 0)
  const int m0 = (wgid / NT) * 256, n0 = (wgid % NT) * 256;
  const int lm = lane & 15;
  const int sw = (lane & 7) << 4;
  const int g16 = (lane >> 4) << 4;
  const size_t strideAB = (size_t)K * 2;  // bytes per row

  auto stageA = [&](int buf, int h, int t) {
#pragma unroll
    for (int p2 = 0; p2 < 2; ++p2) {
      int off = tid * 16 + p2 * 8192;
      int row = off >> 7, cb = off & 127;
      int scb = cb ^ ((row & 7) << 4);
      gload_lds16((const char*)A + (size_t)(m0 + h * 128 + row) * strideAB + t * 128 + scb,
                  lds + buf * 65536 + h * 16384 + off);
    }
  };
  auto stageB = [&](int buf, int h, int t) {
#pragma unroll
    for (int p2 = 0; p2 < 2; ++p2) {
      int off = tid * 16 + p2 * 8192;
      int row = off >> 7, cb = off & 127;
      int scb = cb ^ ((row & 7) << 4);
      gload_lds16((const char*)Bt + (size_t)(n0 + h * 128 + row) * strideAB + t * 128 + scb,
                  lds + buf * 65536 + 32768 + h * 16384 + off);
    }
  };
  auto ldA = [&](int buf, int i, int ks) {
    int row = wm * 128 + i * 16 + lm;
    return *(const short8*)(lds + buf * 65536 + row * 128 + ((ks * 64 + g16) ^ sw));
  };
  auto ldB = [&](int buf, int j, int ks) {
    int row = wn * 64 + j * 16 + lm;
    return *(const short8*)(lds + buf * 65536 + 32768 + row * 128 + ((ks * 64 + g16) ^ sw));
  };

  f32x4 acc[8][4] = {};
  short8 bf_[8];
  const int niter = K / 128;

  stageA(0, 0, 0); stageA(0, 1, 0); stageB(0, 0, 0); stageB(0, 1, 0);
  stageB(1, 0, 1); stageB(1, 1, 1);
  asm volatile("s_waitcnt vmcnt(4)" ::: "memory");
  BAR;

  for (int i = 0; i < niter; ++i) {
    const int t0 = 2 * i, t1 = 2 * i + 1;
    const bool nl = (i + 1 < niter);
    LOADB(0);
    PHASE(0, 0, stageA(1, 0, t1)); BAR;
    PHASE(0, 2, stageA(1, 1, t1)); BAR;
    PHASE(0, 4, if (nl) stageB(0, 0, t0 + 2)); BAR;
    PHASE(0, 6, if (nl) stageB(0, 1, t0 + 2));
    if (nl) { asm volatile("s_waitcnt vmcnt(4)" ::: "memory"); }
    else    { asm volatile("s_waitcnt vmcnt(0)" ::: "memory"); }
    BAR;
    LOADB(1);
    PHASE(1, 0, if (nl) stageA(0, 0, t0 + 2)); BAR;
    PHASE(1, 2, if (nl) stageA(0, 1, t0 + 2)); BAR;
    PHASE(1, 4, if (nl) stageB(1, 0, t1 + 2)); BAR;
    PHASE(1, 6, if (nl) stageB(1, 1, t1 + 2));
    if (nl) { asm volatile("s_waitcnt vmcnt(4)" ::: "memory"); }
    BAR;
  }

  if constexpr (sizeof(OutT) == 2) {
    __syncthreads();
    bf16* sC = (bf16*)lds;
#pragma unroll
    for (int i = 0; i < 8; ++i) {
      int row = wm * 128 + i * 16 + (lane >> 4) * 4;
#pragma unroll
      for (int j = 0; j < 4; ++j) {
        int col = wn * 64 + j * 16 + lm;
#pragma unroll
        for (int r = 0; r < 4; ++r) sC[(row + r) * 256 + col] = __float2bfloat16(acc[i][j][r]);
      }
    }
    __syncthreads();
#pragma unroll
    for (int p = 0; p < 16; ++p) {
      int off = tid * 16 + p * 8192;
      int row = off >> 9, cb = off & 511;
      *(short8*)((char*)C + ((size_t)(m0 + row) * ldC + n0) * 2 + cb) =
          *(const short8*)(lds + off);
    }
  } else {
    // f32 epilogue: LDS-staged in two 128-row halves, coalesced 16B stores
    float* sCf = (float*)lds;
#pragma unroll
    for (int half = 0; half < 2; ++half) {
      __syncthreads();
      if (wm == half) {
#pragma unroll
        for (int i = 0; i < 8; ++i) {
          int row = i * 16 + (lane >> 4) * 4;   // local 0..127
#pragma unroll
          for (int j = 0; j < 4; ++j) {
            int col = wn * 64 + j * 16 + lm;
#pragma unroll
            for (int r = 0; r < 4; ++r) sCf[(row + r) * 256 + col] = acc[i][j][r];
          }
        }
      }
      __syncthreads();
#pragma unroll
      for (int p = 0; p < 16; ++p) {
        int off = tid * 16 + p * 8192;          // 0..131071 bytes
        int row = off >> 10, cb = off & 1023;   // 1024 B per 256-f32 row
        *(f32x4*)((char*)C + ((size_t)(m0 + half * 128 + row) * ldC + n0) * 4 + cb) =
            *(const f32x4*)(lds + off);
      }
    }
  }
}

// ---------------- KV projection GEMM (128x128, m97 structure) + fused epilogue ----------------
__global__ __launch_bounds__(256) void gemm_kv(const bf16* __restrict__ A,
                                               const bf16* __restrict__ Bt,
                                               bf16* __restrict__ qkv,
                                               bf16* __restrict__ vtb,
                                               const float* __restrict__ cosp,
                                               const float* __restrict__ sinp) {
  constexpr int BM = 128, BN = 128, BK = 64, K = 2048, QKVW = 3072, T = 2048, SCP = 132;
  __shared__ char smem[BM * SCP * 2];
  bf16* sA = (bf16*)smem;
  bf16* sB = (bf16*)(smem + 16384);
  int tid = threadIdx.x;
  int lane = tid & 63, w = tid >> 6;
  int flat = blockIdx.x;
  int wgid = (flat & 7) * (gridDim.x >> 3) + (flat >> 3);
  int m0 = (wgid >> 3) * BM, n0 = (wgid & 7) * BN;
  int wm = (w >> 1) * 64, wn = (w & 1) * 64;
  f32x4 acc[4][4] = {};
  for (int kt = 0; kt < K / BK; ++kt) {
    __syncthreads();
    int kb = kt * BK;
#pragma unroll
    for (int it = 0; it < 4; ++it) {
      int off = tid * 16 + it * 4096;
      int row = off >> 7, cb = off & 127;
      gload_lds16((const char*)A + (((size_t)(m0 + row)) * K + kb) * 2 + cb, (char*)sA + off);
    }
#pragma unroll
    for (int it = 0; it < 4; ++it) {
      int off = tid * 16 + it * 4096;
      int row = off >> 7, cb = off & 127;
      gload_lds16((const char*)Bt + (((size_t)(n0 + row)) * K + kb) * 2 + cb, (char*)sB + off);
    }
    asm volatile("s_waitcnt vmcnt(0)" ::: "memory");
    __syncthreads();
#pragma unroll
    for (int ks = 0; ks < 2; ++ks) {
      short8 af[4], bfr[4];
#pragma unroll
      for (int i = 0; i < 4; ++i) {
        af[i]  = *(const short8*)(sA + (wm + i * 16 + (lane & 15)) * BK + ks * 32 + (lane >> 4) * 8);
        bfr[i] = *(const short8*)(sB + (wn + i * 16 + (lane & 15)) * BK + ks * 32 + (lane >> 4) * 8);
      }
#pragma unroll
      for (int i = 0; i < 4; ++i)
#pragma unroll
        for (int j = 0; j < 4; ++j)
          acc[i][j] = MFMA16(af[i], bfr[j], acc[i][j]);
    }
  }

  const int kvh = (n0 >> 7) & 3;
  const int b = m0 >> 11, t0 = m0 & (T - 1);
  bf16* sC = (bf16*)smem;
  __syncthreads();
  if (n0 >= 512) {
    // V tile: transposed store sC_T[d][t_local], then coalesced to vt
#pragma unroll
    for (int i = 0; i < 4; ++i) {
      int row = wm + i * 16 + (lane >> 4) * 4;
#pragma unroll
      for (int j = 0; j < 4; ++j) {
        int col = wn + j * 16 + (lane & 15);
#pragma unroll
        for (int r = 0; r < 4; ++r) sC[col * SCP + row + r] = __float2bfloat16(acc[i][j][r]);
      }
    }
    __syncthreads();
#pragma unroll
    for (int p = 0; p < 8; ++p) {
      int g = p * 2048 + tid * 8;
      int d = g >> 7, tb = g & 127;
      *(short8*)(vtb + ((size_t)((b * 4 + kvh) * 128 + d)) * T + t0 + tb) =
          *(const short8*)(sC + d * SCP + tb);
    }
  } else {
    // K tile: rope+RMS in LDS (2 rows/iter: lane>>5 selects row, 32-lane reduce), linear store
#pragma unroll
    for (int i = 0; i < 4; ++i) {
      int row = wm + i * 16 + (lane >> 4) * 4;
#pragma unroll
      for (int j = 0; j < 4; ++j) {
        int col = wn + j * 16 + (lane & 15);
#pragma unroll
        for (int r = 0; r < 4; ++r) sC[(row + r) * SCP + col] = __float2bfloat16(acc[i][j][r]);
      }
    }
    __syncthreads();
    for (int rr = 0; rr < 16; ++rr) {
      int row = w * 32 + rr * 2 + (lane >> 5);
      int t = t0 + row;
      int dd = lane & 31;
      float x1 = __bfloat162float(sC[row * SCP + dd]);
      float x2 = __bfloat162float(sC[row * SCP + dd + 64]);
      float x3 = __bfloat162float(sC[row * SCP + dd + 32]);
      float x4 = __bfloat162float(sC[row * SCP + dd + 96]);
      float c1 = cosp[t * 64 + dd], s1 = sinp[t * 64 + dd];
      float c2 = cosp[t * 64 + dd + 32], s2 = sinp[t * 64 + dd + 32];
      float o1 = x1 * c1 - x2 * s1, o2 = x1 * s1 + x2 * c1;
      float o3 = x3 * c2 - x4 * s2, o4 = x3 * s2 + x4 * c2;
      float ss = o1 * o1 + o2 * o2 + o3 * o3 + o4 * o4;
#pragma unroll
      for (int m = 1; m < 32; m <<= 1) ss += __shfl_xor(ss, m, 64);
      float r = rsqrtf(ss * (1.f / 128.f) + 1e-5f);
      sC[row * SCP + dd] = __float2bfloat16(o1 * r);
      sC[row * SCP + dd + 64] = __float2bfloat16(o2 * r);
      sC[row * SCP + dd + 32] = __float2bfloat16(o3 * r);
      sC[row * SCP + dd + 96] = __float2bfloat16(o4 * r);
    }
    __syncthreads();
#pragma unroll
    for (int p = 0; p < 8; ++p) {
      int g = p * 2048 + tid * 8;
      int row = g >> 7, cb = g & 127;
      *(short8*)(qkv + (size_t)(m0 + row) * QKVW + 2048 + kvh * 128 + cb) =
          *(const short8*)(sC + row * SCP + cb);
    }
  }
}

// ---------------- flash attention: 8-wave 32x32 swapped-QK^T + fused Q-RoPE/RMS ----------------
// Single barrier per KV-tile. Pairing: bx and bx+256 co-reside on a CU; give them
// SIMILAR durations (7,6),(5,4),(3,2),(1,0) -> makespan 34tau vs 40tau (alpha=1.5 model).
__global__ __launch_bounds__(512, 2) void attn_k(const bf16* __restrict__ qkv,
                                                 const bf16* __restrict__ vt,
                                                 bf16* __restrict__ y,
                                                 const float* __restrict__ cosp,
                                                 const float* __restrict__ sinp) {
  constexpr int T = 2048, Dh = 128, KV = 4, KB = 64, QKVW = 3072, KOFF = 2048;
  __shared__ char lds[65536];
  const int tid = threadIdx.x, lane = tid & 63, w = tid >> 6;
  const int hi = lane >> 5, lq = lane & 31;
  const int bx = blockIdx.x;
  const int g = (bx >> 6) & 3;
  const int qt = (bx < 256) ? (7 - 2 * g) : (6 - 2 * g);  // pairs (7,6),(5,4),(3,2),(1,0)
  const int b = (bx >> 4) & 3, h = bx & 15;
  const int kh = h >> 2;
  const int q0 = qt * 256 + w * 32;
  const int qg = q0 + lq;
  const int swz = (lane & 7) << 4;

  short8 aq[8];
  {
    const bf16* qp = qkv + ((size_t)(b * T + qg)) * QKVW + h * Dh + hi * 8;
#pragma unroll
    for (int m = 0; m < 8; ++m) aq[m] = *(const short8*)(qp + m * 16);
  }
  __builtin_amdgcn_s_waitcnt(0);

  // fused RoPE + RMS on Q; folds 1/sqrt(D) and log2(e)
  {
    float ss = 0.f;
#pragma unroll
    for (int m = 0; m < 8; ++m)
#pragma unroll
      for (int e = 0; e < 8; ++e) { float v = bf2f(aq[m][e]); ss += v * v; }
    ss += __shfl_xor(ss, 32, 64);
    float rn = rsqrtf(ss * (1.f / 128.f) + 1e-5f) * (0.08838834764831845f * 1.4426950408889634f);
    const float4* cq4 = (const float4*)(cosp + (size_t)qg * 64) + hi * 2;
    const float4* sq4 = (const float4*)(sinp + (size_t)qg * 64) + hi * 2;
#pragma unroll
    for (int m = 0; m < 4; ++m) {
      float4 c0 = cq4[m * 4], c1 = cq4[m * 4 + 1];
      float4 s0 = sq4[m * 4], s1 = sq4[m * 4 + 1];
      float cc[8] = {c0.x, c0.y, c0.z, c0.w, c1.x, c1.y, c1.z, c1.w};
      float sn[8] = {s0.x, s0.y, s0.z, s0.w, s1.x, s1.y, s1.z, s1.w};
      short8 xl = aq[m], xh = aq[m + 4], nl, nh;
#pragma unroll
      for (int e = 0; e < 8; ++e) {
        float x1 = bf2f(xl[e]), x2 = bf2f(xh[e]);
        nl[e] = bf_bits((x1 * cc[e] - x2 * sn[e]) * rn);
        nh[e] = bf_bits((x1 * sn[e] + x2 * cc[e]) * rn);
      }
      aq[m] = nl; aq[m + 4] = nh;
    }
  }

  f32x16 acc[4] = {};
  float mrow = -1e4f, lrow = 0.f;

  auto stage = [&](int buf, int kv0) {
#pragma unroll
    for (int p = 0; p < 2; ++p) {        // K: [64 kv][256B]
      int off = tid * 16 + p * 8192;
      int row = off >> 8, cb = off & 255;
      int scb = cb ^ ((row & 7) << 4);
      gload_lds16((const char*)qkv + (((size_t)(b * T + kv0 + row)) * QKVW + KOFF + kh * Dh) * 2 + scb,
                  lds + buf * 16384 + off);
    }
#pragma unroll
    for (int p = 0; p < 2; ++p) {        // V^T: [128 d][128B]
      int off = tid * 16 + p * 8192;
      int row = off >> 7, cb = off & 127;
      int scb = cb ^ ((row & 7) << 4);
      gload_lds16((const char*)vt + (((size_t)((b * KV + kh) * Dh + row)) * T + kv0) * 2 + scb,
                  lds + 32768 + buf * 16384 + off);
    }
  };

  const int nt = (qt + 1) * 4;
  const int lastit = (q0 + 31) >> 6;
  stage(0, 0);
  int cur = 0;

  for (int it = 0; it < nt; ++it) {
    asm volatile("s_waitcnt vmcnt(0)" ::: "memory");
    __builtin_amdgcn_s_barrier();
    if (it + 1 < nt) stage(cur ^ 1, (it + 1) * KB);
    if (it <= lastit) {
      const char* sK = lds + cur * 16384;
      const char* sV = lds + 32768 + cur * 16384;
      const int kv0 = it * KB;

      f32x16 s0 = {}, s1 = {};
      __builtin_amdgcn_s_setprio(1);
#pragma unroll
      for (int m = 0; m < 8; ++m) {
        short8 ak = *(const short8*)(sK + lq * 256 + ((m * 32 + hi * 16) ^ swz));
        s0 = MFMA32(ak, aq[m], s0);
      }
#pragma unroll
      for (int m = 0; m < 8; ++m) {
        short8 ak = *(const short8*)(sK + (32 + lq) * 256 + ((m * 32 + hi * 16) ^ swz));
        s1 = MFMA32(ak, aq[m], s1);
      }
      __builtin_amdgcn_s_setprio(0);

      if (kv0 + 63 > q0) {
#pragma unroll
        for (int r = 0; r < 16; ++r) {
          int krow = (r & 3) + 8 * (r >> 2) + 4 * hi;
          if (kv0 + krow > qg) s0[r] = -1e30f;
          if (kv0 + 32 + krow > qg) s1[r] = -1e30f;
        }
      }

      float mx[16];
#pragma unroll
      for (int r = 0; r < 16; ++r) mx[r] = fmaxf(s0[r], s1[r]);
#pragma unroll
      for (int st = 8; st > 0; st >>= 1)
#pragma unroll
        for (int r = 0; r < 16; ++r) if (r < st) mx[r] = fmaxf(mx[r], mx[r + st]);
      float tmax = fmaxf(mx[0], __shfl_xor(mx[0], 32, 64));
      if (!__all(tmax - mrow <= 11.5f)) {   // defer-max (T13), 8*log2e
        float mn = fmaxf(mrow, tmax);
        float corr = exp2g(mrow - mn);
        mrow = mn;
        lrow *= corr;
#pragma unroll
        for (int dt = 0; dt < 4; ++dt)
#pragma unroll
          for (int r = 0; r < 16; ++r) acc[dt][r] *= corr;
      }
      float sm[16];
#pragma unroll
      for (int r = 0; r < 16; ++r) {
        s0[r] = exp2g(s0[r] - mrow);
        s1[r] = exp2g(s1[r] - mrow);
        sm[r] = s0[r] + s1[r];
      }
#pragma unroll
      for (int st = 8; st > 0; st >>= 1)
#pragma unroll
        for (int r = 0; r < 16; ++r) if (r < st) sm[r] += sm[r + st];
      lrow += sm[0] + __shfl_xor(sm[0], 32, 64);

      unsigned int u[16];
#pragma unroll
      for (int g2 = 0; g2 < 4; ++g2) {
        u[g2 * 2 + 0] = pk2(s0[4 * g2 + 0], s0[4 * g2 + 1]);
        u[g2 * 2 + 1] = pk2(s0[4 * g2 + 2], s0[4 * g2 + 3]);
        u[8 + g2 * 2 + 0] = pk2(s1[4 * g2 + 0], s1[4 * g2 + 1]);
        u[8 + g2 * 2 + 1] = pk2(s1[4 * g2 + 2], s1[4 * g2 + 3]);
      }
      short8 pb[4];
#pragma unroll
      for (int kvs = 0; kvs < 4; ++kvs) {
        unsigned int lo0 = u[4 * kvs + 0], lo1 = u[4 * kvs + 1];
        unsigned int hi0 = u[4 * kvs + 2], hi1 = u[4 * kvs + 3];
        asm volatile("v_permlane32_swap_b32 %0, %1" : "+v"(lo0), "+v"(hi0));
        asm volatile("v_permlane32_swap_b32 %0, %1" : "+v"(lo1), "+v"(hi1));
        union { short8 v; unsigned int q[4]; } P;
        P.q[0] = lo0; P.q[1] = lo1; P.q[2] = hi0; P.q[3] = hi1;
        pb[kvs] = P.v;
      }

      __builtin_amdgcn_s_setprio(1);
#pragma unroll
      for (int dt = 0; dt < 4; ++dt) {
#pragma unroll
        for (int kvs = 0; kvs < 4; ++kvs) {
          short8 av = *(const short8*)(sV + (dt * 32 + lq) * 128 + ((kvs * 32 + hi * 16) ^ swz));
          acc[dt] = MFMA32(av, pb[kvs], acc[dt]);
        }
      }
      __builtin_amdgcn_s_setprio(0);
    }
    cur ^= 1;
  }

  float inv = 1.f / lrow;
  __syncthreads();
  char* myO = lds + w * 8192;
#pragma unroll
  for (int dt = 0; dt < 4; ++dt)
#pragma unroll
    for (int i = 0; i < 8; ++i) {
      int d = ((2 * i) & 3) + 8 * (i >> 1) + 4 * hi;
      unsigned int pkd = pk2(acc[dt][2 * i] * inv, acc[dt][2 * i + 1] * inv);
      *(unsigned int*)(myO + lq * 256 + ((dt * 64 + d * 2) ^ ((lq & 7) << 4))) = pkd;
    }
  __syncthreads();
  const int row0 = b * T + qt * 256;
#pragma unroll
  for (int p = 0; p < 8; ++p) {
    int off = (p * 512 + tid) * 16;
    int q = off >> 8, cb = off & 255;
    short8 v = *(const short8*)(lds + (q >> 5) * 8192 + (q & 31) * 256 + (cb ^ ((q & 7) << 4)));
    *(short8*)((char*)y + ((size_t)(row0 + q) * 2048 + h * 128) * 2 + cb) = v;
  }
}

// ---------------- launch ----------------
extern "C" void kernel_launch(void* const* d_in, const int* in_sizes, int n_in,
                              void* d_out, int out_size, void* d_ws, size_t ws_size,
                              hipStream_t stream) {
  const float* x    = (const float*)d_in[0];
  const float* cosp = (const float*)d_in[1];
  const float* sinp = (const float*)d_in[2];
  const float* wq   = (const float*)d_in[3];
  const float* wk   = (const float*)d_in[4];
  const float* wv   = (const float*)d_in[5];
  const float* wp   = (const float*)d_in[6];
  float* out = (float*)d_out;

  constexpr size_t Mtok = 8192;  // B*T
  constexpr int Cdim = 2048, HD = 2048, KVD = 512, QKVW = 3072;

  char* ws = (char*)d_ws;
  bf16* xb    = (bf16*)ws; ws += Mtok * Cdim * 2;
  bf16* wqkvT = (bf16*)ws; ws += (size_t)QKVW * Cdim * 2;  // rows: wq^T | wk^T | wv^T
  bf16* wpT   = (bf16*)ws; ws += (size_t)Cdim * HD * 2;
  bf16* qkv   = (bf16*)ws; ws += Mtok * QKVW * 2;
  bf16* vtb   = (bf16*)ws; ws += Mtok * KVD * 2;
  bf16* yb    = (bf16*)ws; ws += Mtok * HD * 2;

  // fused prep: x conversion (8192 blocks) + 4 weight transposes (10240 blocks)
  prep_k<<<dim3(18432), 256, 0, stream>>>(x, xb, wq, wk, wv, wp, wqkvT, wpT);

  // Q projection: 256 tiles = exact 1-round packing
  gemm256<bf16><<<dim3(256), 512, 0, stream>>>(xb, wqkvT, qkv, Cdim, 8, QKVW);
  // KV projection + fused K-rope/RMS + V-transpose
  gemm_kv<<<dim3(512), 256, 0, stream>>>(xb, wqkvT + (size_t)2048 * Cdim, qkv, vtb, cosp, sinp);

  attn_k<<<dim3(512), 512, 0, stream>>>(qkv, vtb, yb, cosp, sinp);

  gemm256<float><<<dim3(256), 512, 0, stream>>>(yb, wpT, out, Cdim, 8, 2048);
}

// Round 19
// 300.825 us; speedup vs baseline: 1.1282x; 1.0055x over previous
//
#include <hip/hip_runtime.h>
#include <hip/hip_bf16.h>
#include <stdint.h>

using bf16 = __hip_bfloat16;
typedef __attribute__((ext_vector_type(8))) short short8;
typedef __attribute__((ext_vector_type(4))) float f32x4;
typedef __attribute__((ext_vector_type(16))) float f32x16;

#define MFMA16(a,b,c) __builtin_amdgcn_mfma_f32_16x16x32_bf16(a,b,c,0,0,0)
#define MFMA32(a,b,c) __builtin_amdgcn_mfma_f32_32x32x16_bf16(a,b,c,0,0,0)

__device__ __forceinline__ void gload_lds16(const void* g, void* l) {
  __builtin_amdgcn_global_load_lds((const __attribute__((address_space(1))) void*)g,
                                   (__attribute__((address_space(3))) void*)l, 16, 0, 0);
}

__device__ __forceinline__ short bf_bits(float f) {
  bf16 h = __float2bfloat16(f);
  return *reinterpret_cast<short*>(&h);
}
// hardware packed f32->bf16 (RNE), low = a, high = b  [T12]
__device__ __forceinline__ unsigned int pk2(float a, float b) {
  unsigned int r;
  asm("v_cvt_pk_bf16_f32 %0, %1, %2" : "=v"(r) : "v"(a), "v"(b));
  return r;
}
__device__ __forceinline__ float bf2f(short s) {
  return __uint_as_float((unsigned int)(unsigned short)s << 16);
}
__device__ __forceinline__ float exp2g(float x) { return __builtin_amdgcn_exp2f(x); }

// ---------------- fused prep: x f32->bf16 (blocks 0..8191) + 4 weight transposes ----------------
__global__ __launch_bounds__(256) void prep_k(const float* __restrict__ x, bf16* __restrict__ xb,
                                              const float* __restrict__ wq, const float* __restrict__ wk,
                                              const float* __restrict__ wv, const float* __restrict__ wp,
                                              bf16* __restrict__ wqkvT, bf16* __restrict__ wpT) {
  __shared__ float tile[32][33];
  int bid = blockIdx.x;
  if (bid < 8192) {  // x conversion, 8 elems/thread
    size_t i = ((size_t)bid * 256 + threadIdx.x) * 8;
    float4 a = *(const float4*)(x + i);
    float4 b = *(const float4*)(x + i + 4);
    short8 pk;
    pk[0] = bf_bits(a.x); pk[1] = bf_bits(a.y); pk[2] = bf_bits(a.z); pk[3] = bf_bits(a.w);
    pk[4] = bf_bits(b.x); pk[5] = bf_bits(b.y); pk[6] = bf_bits(b.z); pk[7] = bf_bits(b.w);
    *(short8*)(xb + i) = pk;
    return;
  }
  bid -= 8192;
  const float* in; bf16* out; int N, loc;
  constexpr int K = 2048;
  if (bid < 4096)      { in = wq; out = wqkvT;                        N = 2048; loc = bid; }
  else if (bid < 5120) { in = wk; out = wqkvT + (size_t)2048 * K;     N = 512;  loc = bid - 4096; }
  else if (bid < 6144) { in = wv; out = wqkvT + (size_t)2560 * K;     N = 512;  loc = bid - 5120; }
  else                 { in = wp; out = wpT;                          N = 2048; loc = bid - 6144; }
  int nb = N >> 5;
  int n0 = (loc % nb) * 32, k0 = (loc / nb) * 32;
  int tx = threadIdx.x & 31, ty = threadIdx.x >> 5;  // 32 x 8
#pragma unroll
  for (int j = 0; j < 4; ++j) {
    int kk = ty + j * 8;
    tile[kk][tx] = in[(size_t)(k0 + kk) * N + n0 + tx];
  }
  __syncthreads();
#pragma unroll
  for (int j = 0; j < 4; ++j) {
    int nn = ty + j * 8;
    out[(size_t)(n0 + nn) * K + k0 + tx] = __float2bfloat16(tile[tx][nn]);
  }
}

// ---------------- 256x256 8-phase bf16 GEMM: C[.][ldC] = A[M][K] * Bt[N][K]^T ----------------
#define PHASE(buf, i0, ...)                                                       \
  {                                                                               \
    short8 a00 = ldA(buf, i0, 0), a01 = ldA(buf, i0, 1);                          \
    short8 a10 = ldA(buf, (i0) + 1, 0), a11 = ldA(buf, (i0) + 1, 1);              \
    __VA_ARGS__;                                                                  \
    __builtin_amdgcn_s_barrier();                                                 \
    asm volatile("s_waitcnt lgkmcnt(0)" ::: "memory");                            \
    __builtin_amdgcn_s_setprio(1);                                                \
    _Pragma("unroll") for (int j = 0; j < 4; ++j) {                               \
      acc[i0][j] = MFMA16(a00, bf_[2 * j], acc[i0][j]);                           \
      acc[i0][j] = MFMA16(a01, bf_[2 * j + 1], acc[i0][j]);                       \
      acc[(i0) + 1][j] = MFMA16(a10, bf_[2 * j], acc[(i0) + 1][j]);               \
      acc[(i0) + 1][j] = MFMA16(a11, bf_[2 * j + 1], acc[(i0) + 1][j]);           \
    }                                                                             \
    __builtin_amdgcn_s_setprio(0);                                                \
  }
#define LOADB(buf)                                                                \
  _Pragma("unroll") for (int j = 0; j < 4; ++j) {                                 \
    bf_[2 * j] = ldB(buf, j, 0);                                                  \
    bf_[2 * j + 1] = ldB(buf, j, 1);                                              \
  }
#define BAR __builtin_amdgcn_s_barrier()

template <typename OutT>
__global__ __launch_bounds__(512, 2) void gemm256(const bf16* __restrict__ A,
                                                  const bf16* __restrict__ Bt,
                                                  OutT* __restrict__ C, int K,
                                                  int NT, int ldC) {
  __shared__ char lds[131072];
  const int tid = threadIdx.x, lane = tid & 63, w = tid >> 6;
  const int wm = w >> 2, wn = w & 3;
  const int bx = blockIdx.x;
  const int chunk = gridDim.x >> 3;
  const int wgid = (bx & 7) * chunk + (bx >> 3);   // XCD-bijective (grid % 8 == 0)
  const int m0 = (wgid / NT) * 256, n0 = (wgid % NT) * 256;
  const int lm = lane & 15;
  const int sw = (lane & 7) << 4;
  const int g16 = (lane >> 4) << 4;
  const size_t strideAB = (size_t)K * 2;  // bytes per row

  auto stageA = [&](int buf, int h, int t) {
#pragma unroll
    for (int p2 = 0; p2 < 2; ++p2) {
      int off = tid * 16 + p2 * 8192;
      int row = off >> 7, cb = off & 127;
      int scb = cb ^ ((row & 7) << 4);
      gload_lds16((const char*)A + (size_t)(m0 + h * 128 + row) * strideAB + t * 128 + scb,
                  lds + buf * 65536 + h * 16384 + off);
    }
  };
  auto stageB = [&](int buf, int h, int t) {
#pragma unroll
    for (int p2 = 0; p2 < 2; ++p2) {
      int off = tid * 16 + p2 * 8192;
      int row = off >> 7, cb = off & 127;
      int scb = cb ^ ((row & 7) << 4);
      gload_lds16((const char*)Bt + (size_t)(n0 + h * 128 + row) * strideAB + t * 128 + scb,
                  lds + buf * 65536 + 32768 + h * 16384 + off);
    }
  };
  auto ldA = [&](int buf, int i, int ks) {
    int row = wm * 128 + i * 16 + lm;
    return *(const short8*)(lds + buf * 65536 + row * 128 + ((ks * 64 + g16) ^ sw));
  };
  auto ldB = [&](int buf, int j, int ks) {
    int row = wn * 64 + j * 16 + lm;
    return *(const short8*)(lds + buf * 65536 + 32768 + row * 128 + ((ks * 64 + g16) ^ sw));
  };

  f32x4 acc[8][4] = {};
  short8 bf_[8];
  const int niter = K / 128;

  stageA(0, 0, 0); stageA(0, 1, 0); stageB(0, 0, 0); stageB(0, 1, 0);
  stageB(1, 0, 1); stageB(1, 1, 1);
  asm volatile("s_waitcnt vmcnt(4)" ::: "memory");
  BAR;

  for (int i = 0; i < niter; ++i) {
    const int t0 = 2 * i, t1 = 2 * i + 1;
    const bool nl = (i + 1 < niter);
    LOADB(0);
    PHASE(0, 0, stageA(1, 0, t1)); BAR;
    PHASE(0, 2, stageA(1, 1, t1)); BAR;
    PHASE(0, 4, if (nl) stageB(0, 0, t0 + 2)); BAR;
    PHASE(0, 6, if (nl) stageB(0, 1, t0 + 2));
    if (nl) { asm volatile("s_waitcnt vmcnt(4)" ::: "memory"); }
    else    { asm volatile("s_waitcnt vmcnt(0)" ::: "memory"); }
    BAR;
    LOADB(1);
    PHASE(1, 0, if (nl) stageA(0, 0, t0 + 2)); BAR;
    PHASE(1, 2, if (nl) stageA(0, 1, t0 + 2)); BAR;
    PHASE(1, 4, if (nl) stageB(1, 0, t1 + 2)); BAR;
    PHASE(1, 6, if (nl) stageB(1, 1, t1 + 2));
    if (nl) { asm volatile("s_waitcnt vmcnt(4)" ::: "memory"); }
    BAR;
  }

  if constexpr (sizeof(OutT) == 2) {
    __syncthreads();
    bf16* sC = (bf16*)lds;
#pragma unroll
    for (int i = 0; i < 8; ++i) {
      int row = wm * 128 + i * 16 + (lane >> 4) * 4;
#pragma unroll
      for (int j = 0; j < 4; ++j) {
        int col = wn * 64 + j * 16 + lm;
#pragma unroll
        for (int r = 0; r < 4; ++r) sC[(row + r) * 256 + col] = __float2bfloat16(acc[i][j][r]);
      }
    }
    __syncthreads();
#pragma unroll
    for (int p = 0; p < 16; ++p) {
      int off = tid * 16 + p * 8192;
      int row = off >> 9, cb = off & 511;
      *(short8*)((char*)C + ((size_t)(m0 + row) * ldC + n0) * 2 + cb) =
          *(const short8*)(lds + off);
    }
  } else {
    // f32 epilogue: LDS-staged in two 128-row halves, coalesced 16B stores
    float* sCf = (float*)lds;
#pragma unroll
    for (int half = 0; half < 2; ++half) {
      __syncthreads();
      if (wm == half) {
#pragma unroll
        for (int i = 0; i < 8; ++i) {
          int row = i * 16 + (lane >> 4) * 4;   // local 0..127
#pragma unroll
          for (int j = 0; j < 4; ++j) {
            int col = wn * 64 + j * 16 + lm;
#pragma unroll
            for (int r = 0; r < 4; ++r) sCf[(row + r) * 256 + col] = acc[i][j][r];
          }
        }
      }
      __syncthreads();
#pragma unroll
      for (int p = 0; p < 16; ++p) {
        int off = tid * 16 + p * 8192;          // 0..131071 bytes
        int row = off >> 10, cb = off & 1023;   // 1024 B per 256-f32 row
        *(f32x4*)((char*)C + ((size_t)(m0 + half * 128 + row) * ldC + n0) * 4 + cb) =
            *(const f32x4*)(lds + off);
      }
    }
  }
}

// ---------------- KV projection GEMM (128x128, m97 structure) + fused epilogue ----------------
__global__ __launch_bounds__(256) void gemm_kv(const bf16* __restrict__ A,
                                               const bf16* __restrict__ Bt,
                                               bf16* __restrict__ qkv,
                                               bf16* __restrict__ vtb,
                                               const float* __restrict__ cosp,
                                               const float* __restrict__ sinp) {
  constexpr int BM = 128, BN = 128, BK = 64, K = 2048, QKVW = 3072, T = 2048, SCP = 132;
  __shared__ char smem[BM * SCP * 2];
  bf16* sA = (bf16*)smem;
  bf16* sB = (bf16*)(smem + 16384);
  int tid = threadIdx.x;
  int lane = tid & 63, w = tid >> 6;
  int flat = blockIdx.x;
  int wgid = (flat & 7) * (gridDim.x >> 3) + (flat >> 3);
  int m0 = (wgid >> 3) * BM, n0 = (wgid & 7) * BN;
  int wm = (w >> 1) * 64, wn = (w & 1) * 64;
  f32x4 acc[4][4] = {};
  for (int kt = 0; kt < K / BK; ++kt) {
    __syncthreads();
    int kb = kt * BK;
#pragma unroll
    for (int it = 0; it < 4; ++it) {
      int off = tid * 16 + it * 4096;
      int row = off >> 7, cb = off & 127;
      gload_lds16((const char*)A + (((size_t)(m0 + row)) * K + kb) * 2 + cb, (char*)sA + off);
    }
#pragma unroll
    for (int it = 0; it < 4; ++it) {
      int off = tid * 16 + it * 4096;
      int row = off >> 7, cb = off & 127;
      gload_lds16((const char*)Bt + (((size_t)(n0 + row)) * K + kb) * 2 + cb, (char*)sB + off);
    }
    asm volatile("s_waitcnt vmcnt(0)" ::: "memory");
    __syncthreads();
#pragma unroll
    for (int ks = 0; ks < 2; ++ks) {
      short8 af[4], bfr[4];
#pragma unroll
      for (int i = 0; i < 4; ++i) {
        af[i]  = *(const short8*)(sA + (wm + i * 16 + (lane & 15)) * BK + ks * 32 + (lane >> 4) * 8);
        bfr[i] = *(const short8*)(sB + (wn + i * 16 + (lane & 15)) * BK + ks * 32 + (lane >> 4) * 8);
      }
#pragma unroll
      for (int i = 0; i < 4; ++i)
#pragma unroll
        for (int j = 0; j < 4; ++j)
          acc[i][j] = MFMA16(af[i], bfr[j], acc[i][j]);
    }
  }

  const int kvh = (n0 >> 7) & 3;
  const int b = m0 >> 11, t0 = m0 & (T - 1);
  bf16* sC = (bf16*)smem;
  __syncthreads();
  if (n0 >= 512) {
    // V tile: transposed store sC_T[d][t_local], then coalesced to vt
#pragma unroll
    for (int i = 0; i < 4; ++i) {
      int row = wm + i * 16 + (lane >> 4) * 4;
#pragma unroll
      for (int j = 0; j < 4; ++j) {
        int col = wn + j * 16 + (lane & 15);
#pragma unroll
        for (int r = 0; r < 4; ++r) sC[col * SCP + row + r] = __float2bfloat16(acc[i][j][r]);
      }
    }
    __syncthreads();
#pragma unroll
    for (int p = 0; p < 8; ++p) {
      int g = p * 2048 + tid * 8;
      int d = g >> 7, tb = g & 127;
      *(short8*)(vtb + ((size_t)((b * 4 + kvh) * 128 + d)) * T + t0 + tb) =
          *(const short8*)(sC + d * SCP + tb);
    }
  } else {
    // K tile: rope+RMS in LDS (2 rows/iter: lane>>5 selects row, 32-lane reduce), linear store
#pragma unroll
    for (int i = 0; i < 4; ++i) {
      int row = wm + i * 16 + (lane >> 4) * 4;
#pragma unroll
      for (int j = 0; j < 4; ++j) {
        int col = wn + j * 16 + (lane & 15);
#pragma unroll
        for (int r = 0; r < 4; ++r) sC[(row + r) * SCP + col] = __float2bfloat16(acc[i][j][r]);
      }
    }
    __syncthreads();
    for (int rr = 0; rr < 16; ++rr) {
      int row = w * 32 + rr * 2 + (lane >> 5);
      int t = t0 + row;
      int dd = lane & 31;
      float x1 = __bfloat162float(sC[row * SCP + dd]);
      float x2 = __bfloat162float(sC[row * SCP + dd + 64]);
      float x3 = __bfloat162float(sC[row * SCP + dd + 32]);
      float x4 = __bfloat162float(sC[row * SCP + dd + 96]);
      float c1 = cosp[t * 64 + dd], s1 = sinp[t * 64 + dd];
      float c2 = cosp[t * 64 + dd + 32], s2 = sinp[t * 64 + dd + 32];
      float o1 = x1 * c1 - x2 * s1, o2 = x1 * s1 + x2 * c1;
      float o3 = x3 * c2 - x4 * s2, o4 = x3 * s2 + x4 * c2;
      float ss = o1 * o1 + o2 * o2 + o3 * o3 + o4 * o4;
#pragma unroll
      for (int m = 1; m < 32; m <<= 1) ss += __shfl_xor(ss, m, 64);
      float r = rsqrtf(ss * (1.f / 128.f) + 1e-5f);
      sC[row * SCP + dd] = __float2bfloat16(o1 * r);
      sC[row * SCP + dd + 64] = __float2bfloat16(o2 * r);
      sC[row * SCP + dd + 32] = __float2bfloat16(o3 * r);
      sC[row * SCP + dd + 96] = __float2bfloat16(o4 * r);
    }
    __syncthreads();
#pragma unroll
    for (int p = 0; p < 8; ++p) {
      int g = p * 2048 + tid * 8;
      int row = g >> 7, cb = g & 127;
      *(short8*)(qkv + (size_t)(m0 + row) * QKVW + 2048 + kvh * 128 + cb) =
          *(const short8*)(sC + row * SCP + cb);
    }
  }
}

// ---------------- flash attention: 8-wave 32x32 swapped-QK^T + fused Q-RoPE/RMS ----------------
// Single barrier per KV-tile. Pairing: bx and bx+256 co-reside on a CU; give them
// SIMILAR durations (7,6),(5,4),(3,2),(1,0) -> makespan 34tau vs 40tau (alpha=1.5 model).
__global__ __launch_bounds__(512, 2) void attn_k(const bf16* __restrict__ qkv,
                                                 const bf16* __restrict__ vt,
                                                 bf16* __restrict__ y,
                                                 const float* __restrict__ cosp,
                                                 const float* __restrict__ sinp) {
  constexpr int T = 2048, Dh = 128, KV = 4, KB = 64, QKVW = 3072, KOFF = 2048;
  __shared__ char lds[65536];
  const int tid = threadIdx.x, lane = tid & 63, w = tid >> 6;
  const int hi = lane >> 5, lq = lane & 31;
  const int bx = blockIdx.x;
  const int g = (bx >> 6) & 3;
  const int qt = (bx < 256) ? (7 - 2 * g) : (6 - 2 * g);  // pairs (7,6),(5,4),(3,2),(1,0)
  const int b = (bx >> 4) & 3, h = bx & 15;
  const int kh = h >> 2;
  const int q0 = qt * 256 + w * 32;
  const int qg = q0 + lq;
  const int swz = (lane & 7) << 4;

  short8 aq[8];
  {
    const bf16* qp = qkv + ((size_t)(b * T + qg)) * QKVW + h * Dh + hi * 8;
#pragma unroll
    for (int m = 0; m < 8; ++m) aq[m] = *(const short8*)(qp + m * 16);
  }
  __builtin_amdgcn_s_waitcnt(0);

  // fused RoPE + RMS on Q; folds 1/sqrt(D) and log2(e)
  {
    float ss = 0.f;
#pragma unroll
    for (int m = 0; m < 8; ++m)
#pragma unroll
      for (int e = 0; e < 8; ++e) { float v = bf2f(aq[m][e]); ss += v * v; }
    ss += __shfl_xor(ss, 32, 64);
    float rn = rsqrtf(ss * (1.f / 128.f) + 1e-5f) * (0.08838834764831845f * 1.4426950408889634f);
    const float4* cq4 = (const float4*)(cosp + (size_t)qg * 64) + hi * 2;
    const float4* sq4 = (const float4*)(sinp + (size_t)qg * 64) + hi * 2;
#pragma unroll
    for (int m = 0; m < 4; ++m) {
      float4 c0 = cq4[m * 4], c1 = cq4[m * 4 + 1];
      float4 s0 = sq4[m * 4], s1 = sq4[m * 4 + 1];
      float cc[8] = {c0.x, c0.y, c0.z, c0.w, c1.x, c1.y, c1.z, c1.w};
      float sn[8] = {s0.x, s0.y, s0.z, s0.w, s1.x, s1.y, s1.z, s1.w};
      short8 xl = aq[m], xh = aq[m + 4], nl, nh;
#pragma unroll
      for (int e = 0; e < 8; ++e) {
        float x1 = bf2f(xl[e]), x2 = bf2f(xh[e]);
        nl[e] = bf_bits((x1 * cc[e] - x2 * sn[e]) * rn);
        nh[e] = bf_bits((x1 * sn[e] + x2 * cc[e]) * rn);
      }
      aq[m] = nl; aq[m + 4] = nh;
    }
  }

  f32x16 acc[4] = {};
  float mrow = -1e4f, lrow = 0.f;

  auto stage = [&](int buf, int kv0) {
#pragma unroll
    for (int p = 0; p < 2; ++p) {        // K: [64 kv][256B]
      int off = tid * 16 + p * 8192;
      int row = off >> 8, cb = off & 255;
      int scb = cb ^ ((row & 7) << 4);
      gload_lds16((const char*)qkv + (((size_t)(b * T + kv0 + row)) * QKVW + KOFF + kh * Dh) * 2 + scb,
                  lds + buf * 16384 + off);
    }
#pragma unroll
    for (int p = 0; p < 2; ++p) {        // V^T: [128 d][128B]
      int off = tid * 16 + p * 8192;
      int row = off >> 7, cb = off & 127;
      int scb = cb ^ ((row & 7) << 4);
      gload_lds16((const char*)vt + (((size_t)((b * KV + kh) * Dh + row)) * T + kv0) * 2 + scb,
                  lds + 32768 + buf * 16384 + off);
    }
  };

  const int nt = (qt + 1) * 4;
  const int lastit = (q0 + 31) >> 6;
  stage(0, 0);
  int cur = 0;

  for (int it = 0; it < nt; ++it) {
    asm volatile("s_waitcnt vmcnt(0)" ::: "memory");
    __builtin_amdgcn_s_barrier();
    if (it + 1 < nt) stage(cur ^ 1, (it + 1) * KB);
    if (it <= lastit) {
      const char* sK = lds + cur * 16384;
      const char* sV = lds + 32768 + cur * 16384;
      const int kv0 = it * KB;

      f32x16 s0 = {}, s1 = {};
      __builtin_amdgcn_s_setprio(1);
#pragma unroll
      for (int m = 0; m < 8; ++m) {
        short8 ak = *(const short8*)(sK + lq * 256 + ((m * 32 + hi * 16) ^ swz));
        s0 = MFMA32(ak, aq[m], s0);
      }
#pragma unroll
      for (int m = 0; m < 8; ++m) {
        short8 ak = *(const short8*)(sK + (32 + lq) * 256 + ((m * 32 + hi * 16) ^ swz));
        s1 = MFMA32(ak, aq[m], s1);
      }
      __builtin_amdgcn_s_setprio(0);

      if (kv0 + 63 > q0) {
#pragma unroll
        for (int r = 0; r < 16; ++r) {
          int krow = (r & 3) + 8 * (r >> 2) + 4 * hi;
          if (kv0 + krow > qg) s0[r] = -1e30f;
          if (kv0 + 32 + krow > qg) s1[r] = -1e30f;
        }
      }

      float mx[16];
#pragma unroll
      for (int r = 0; r < 16; ++r) mx[r] = fmaxf(s0[r], s1[r]);
#pragma unroll
      for (int st = 8; st > 0; st >>= 1)
#pragma unroll
        for (int r = 0; r < 16; ++r) if (r < st) mx[r] = fmaxf(mx[r], mx[r + st]);
      float tmax = fmaxf(mx[0], __shfl_xor(mx[0], 32, 64));
      if (!__all(tmax - mrow <= 11.5f)) {   // defer-max (T13), 8*log2e
        float mn = fmaxf(mrow, tmax);
        float corr = exp2g(mrow - mn);
        mrow = mn;
        lrow *= corr;
#pragma unroll
        for (int dt = 0; dt < 4; ++dt)
#pragma unroll
          for (int r = 0; r < 16; ++r) acc[dt][r] *= corr;
      }
      float sm[16];
#pragma unroll
      for (int r = 0; r < 16; ++r) {
        s0[r] = exp2g(s0[r] - mrow);
        s1[r] = exp2g(s1[r] - mrow);
        sm[r] = s0[r] + s1[r];
      }
#pragma unroll
      for (int st = 8; st > 0; st >>= 1)
#pragma unroll
        for (int r = 0; r < 16; ++r) if (r < st) sm[r] += sm[r + st];
      lrow += sm[0] + __shfl_xor(sm[0], 32, 64);

      unsigned int u[16];
#pragma unroll
      for (int g2 = 0; g2 < 4; ++g2) {
        u[g2 * 2 + 0] = pk2(s0[4 * g2 + 0], s0[4 * g2 + 1]);
        u[g2 * 2 + 1] = pk2(s0[4 * g2 + 2], s0[4 * g2 + 3]);
        u[8 + g2 * 2 + 0] = pk2(s1[4 * g2 + 0], s1[4 * g2 + 1]);
        u[8 + g2 * 2 + 1] = pk2(s1[4 * g2 + 2], s1[4 * g2 + 3]);
      }
      short8 pb[4];
#pragma unroll
      for (int kvs = 0; kvs < 4; ++kvs) {
        unsigned int lo0 = u[4 * kvs + 0], lo1 = u[4 * kvs + 1];
        unsigned int hi0 = u[4 * kvs + 2], hi1 = u[4 * kvs + 3];
        asm volatile("v_permlane32_swap_b32 %0, %1" : "+v"(lo0), "+v"(hi0));
        asm volatile("v_permlane32_swap_b32 %0, %1" : "+v"(lo1), "+v"(hi1));
        union { short8 v; unsigned int q[4]; } P;
        P.q[0] = lo0; P.q[1] = lo1; P.q[2] = hi0; P.q[3] = hi1;
        pb[kvs] = P.v;
      }

      __builtin_amdgcn_s_setprio(1);
#pragma unroll
      for (int dt = 0; dt < 4; ++dt) {
#pragma unroll
        for (int kvs = 0; kvs < 4; ++kvs) {
          short8 av = *(const short8*)(sV + (dt * 32 + lq) * 128 + ((kvs * 32 + hi * 16) ^ swz));
          acc[dt] = MFMA32(av, pb[kvs], acc[dt]);
        }
      }
      __builtin_amdgcn_s_setprio(0);
    }
    cur ^= 1;
  }

  float inv = 1.f / lrow;
  __syncthreads();
  char* myO = lds + w * 8192;
#pragma unroll
  for (int dt = 0; dt < 4; ++dt)
#pragma unroll
    for (int i = 0; i < 8; ++i) {
      int d = ((2 * i) & 3) + 8 * (i >> 1) + 4 * hi;
      unsigned int pkd = pk2(acc[dt][2 * i] * inv, acc[dt][2 * i + 1] * inv);
      *(unsigned int*)(myO + lq * 256 + ((dt * 64 + d * 2) ^ ((lq & 7) << 4))) = pkd;
    }
  __syncthreads();
  const int row0 = b * T + qt * 256;
#pragma unroll
  for (int p = 0; p < 8; ++p) {
    int off = (p * 512 + tid) * 16;
    int q = off >> 8, cb = off & 255;
    short8 v = *(const short8*)(lds + (q >> 5) * 8192 + (q & 31) * 256 + (cb ^ ((q & 7) << 4)));
    *(short8*)((char*)y + ((size_t)(row0 + q) * 2048 + h * 128) * 2 + cb) = v;
  }
}

// ---------------- launch ----------------
extern "C" void kernel_launch(void* const* d_in, const int* in_sizes, int n_in,
                              void* d_out, int out_size, void* d_ws, size_t ws_size,
                              hipStream_t stream) {
  const float* x    = (const float*)d_in[0];
  const float* cosp = (const float*)d_in[1];
  const float* sinp = (const float*)d_in[2];
  const float* wq   = (const float*)d_in[3];
  const float* wk   = (const float*)d_in[4];
  const float* wv   = (const float*)d_in[5];
  const float* wp   = (const float*)d_in[6];
  float* out = (float*)d_out;

  constexpr size_t Mtok = 8192;  // B*T
  constexpr int Cdim = 2048, HD = 2048, KVD = 512, QKVW = 3072;

  char* ws = (char*)d_ws;
  bf16* xb    = (bf16*)ws; ws += Mtok * Cdim * 2;
  bf16* wqkvT = (bf16*)ws; ws += (size_t)QKVW * Cdim * 2;  // rows: wq^T | wk^T | wv^T
  bf16* wpT   = (bf16*)ws; ws += (size_t)Cdim * HD * 2;
  bf16* qkv   = (bf16*)ws; ws += Mtok * QKVW * 2;
  bf16* vtb   = (bf16*)ws; ws += Mtok * KVD * 2;
  bf16* yb    = (bf16*)ws; ws += Mtok * HD * 2;

  // fused prep: x conversion (8192 blocks) + 4 weight transposes (10240 blocks)
  prep_k<<<dim3(18432), 256, 0, stream>>>(x, xb, wq, wk, wv, wp, wqkvT, wpT);

  // Q projection: 256 tiles = exact 1-round packing
  gemm256<bf16><<<dim3(256), 512, 0, stream>>>(xb, wqkvT, qkv, Cdim, 8, QKVW);
  // KV projection + fused K-rope/RMS + V-transpose
  gemm_kv<<<dim3(512), 256, 0, stream>>>(xb, wqkvT + (size_t)2048 * Cdim, qkv, vtb, cosp, sinp);

  attn_k<<<dim3(512), 512, 0, stream>>>(qkv, vtb, yb, cosp, sinp);

  gemm256<float><<<dim3(256), 512, 0, stream>>>(yb, wpT, out, Cdim, 8, 2048);
}